// Round 11
// baseline (1162.758 us; speedup 1.0000x reference)
//
#include <hip/hip_runtime.h>

typedef unsigned short u16;
typedef unsigned int u32;

#define W_ 224
#define H_ 128
#define C_ 128
#define NH 8
#define HD 16
#define ROWS_ (W_ * H_)          // 28672 rows per image
#define PREP_STRIDE 4128
#define KSTR 40
#define VSTR 232
#define TROWS 64                 // rows per tab_kernel block (R11: 32->64)

typedef __bf16 bf16x8 __attribute__((ext_vector_type(8)));
typedef float f32x4 __attribute__((ext_vector_type(4)));

__device__ __forceinline__ u16 f2bf(float f) {
  u32 u = __float_as_uint(f);
  return (u16)((u + 0x7FFFu + ((u >> 16) & 1u)) >> 16);
}
// Packed RNE f32->bf16 pair: single v_cvt_pk_bf16_f32 (same rounding as f2bf).
__device__ __forceinline__ u32 cvtpk(float lo, float hi) {
  u32 r;
  asm("v_cvt_pk_bf16_f32 %0, %1, %2" : "=v"(r) : "v"(lo), "v"(hi));
  return r;
}
__device__ __forceinline__ float bflo(u32 u) { return __uint_as_float(u << 16); }
__device__ __forceinline__ float bfhi(u32 u) { return __uint_as_float(u & 0xFFFF0000u); }

#if __has_builtin(__builtin_amdgcn_exp2f)
#define EX2(x) __builtin_amdgcn_exp2f(x)
#else
#define EX2(x) __expf((x) * 0.6931471805599453f)
#endif

// ---------------------------------------------------------------------------
// Rank-1 PE decomposition prep: grid (12 s, 8 e-groups), LDS-staged, coalesced.
// ---------------------------------------------------------------------------
__global__ __launch_bounds__(256) void prep_kernel(
    const float* __restrict__ self_Wi, const float* __restrict__ self_bi,
    const float* __restrict__ cross_Wi, const float* __restrict__ cross_bi,
    float* __restrict__ prep) {
  __shared__ float Wq[16][132];
  __shared__ float Wk[16][132];
  __shared__ float u[128];
  __shared__ float Aq[16], Ak[16], bq[16], bk[16];
  const int s = blockIdx.x, e = blockIdx.y, l = s >> 1;
  const float* Wi = (s & 1) ? cross_Wi + (size_t)l * 384 * 128 : self_Wi + (size_t)l * 384 * 128;
  const float* bi = (s & 1) ? cross_bi + l * 384 : self_bi + l * 384;
  const int tid = threadIdx.x;
  if (tid < 128) {
    float ex = (float)(tid & ~1) * (1.f / 128.f);
    u[tid] = expf(-ex * logf(10000.f));
  }
  if (tid >= 128 && tid < 144) { int r = tid - 128; bq[r] = bi[e * 16 + r]; }
  if (tid >= 160 && tid < 176) { int r = tid - 160; bk[r] = bi[128 + e * 16 + r]; }
  for (int t = tid; t < 2048; t += 256) {
    int r = t >> 7, f = t & 127;
    Wq[r][f] = Wi[(size_t)(e * 16 + r) * 128 + f];
    Wk[r][f] = Wi[(size_t)(128 + e * 16 + r) * 128 + f];
  }
  __syncthreads();
  {
    const int grp = tid >> 3;
    const int lg = tid & 7;
    const float* row = (grp < 16) ? Wq[grp] : Wk[grp - 16];
    float a = 0.f;
#pragma unroll
    for (int i = 0; i < 16; ++i) a += row[lg * 16 + i] * u[lg * 16 + i];
    a += __shfl_xor(a, 1);
    a += __shfl_xor(a, 2);
    a += __shfl_xor(a, 4);
    if (lg == 0) {
      if (grp < 16) Aq[grp] = a;
      else          Ak[grp - 16] = a;
    }
  }
  __syncthreads();
  float* out = prep + (size_t)s * PREP_STRIDE;
  for (int t = tid; t < 512; t += 256) {
    int v = t >> 7, f = t & 127;
    float acc = 0.f;
#pragma unroll
    for (int c = 0; c < 16; ++c) {
      if (v == 0)      acc += Wq[c][f] * Ak[c];
      else if (v == 1) acc += Wq[c][f] * bk[c];
      else if (v == 2) acc += Wk[c][f] * Aq[c];
      else             acc += Wk[c][f] * bq[c];
    }
    out[v * 1024 + e * 128 + f] = acc * 0.25f;
  }
  if (tid < 4) {
    int v = tid;
    float acc = 0.f;
#pragma unroll
    for (int c = 0; c < 16; ++c) {
      if (v == 0)      acc += bq[c] * Ak[c];
      else if (v == 1) acc += bq[c] * bk[c];
      else if (v == 2) acc += bk[c] * Aq[c];
      else             acc += bk[c] * bq[c];
    }
    out[4096 + v * 8 + e] = acc * 0.25f;
  }
}

// ---------------------------------------------------------------------------
// Fused LN + affine-PE tables, R11: 64 rows per block, 8 outputs/thread in a
// 2x4 (rows x cols) map. Thread (e=tid&7, rg=tid>>3) owns rows {2rg,2rg+1},
// cols {e, e+8, e+16, e+24} -> one col per table, identical output-row index
// b_out*8+e. Reads: (2+4)*32 = 192 b128 for 8 outputs (24/output, -25% vs
// R10's 32/output); ws staged once per 64 rows; barriers halved. w-reads
// conflict-free ((c+f4)%8 spans all 8 quad-banks), y-reads 2-way (free).
// half is BLOCK-uniform (64 | 28672) -> mode-1 branch uniform. Per-output dot
// order and combine unchanged -> tables bit-identical.
// ---------------------------------------------------------------------------
__global__ __launch_bounds__(256) void tab_kernel(
    float* __restrict__ x, const float* __restrict__ g,
    const float* __restrict__ b, const float* __restrict__ wq,
    const float* __restrict__ cq, float* __restrict__ outA, float* __restrict__ outB,
    const float* __restrict__ wk, const float* __restrict__ ck,
    float* __restrict__ outG, float* __restrict__ outD,
    u16* __restrict__ xb, int mode) {
  __shared__ float ys[TROWS][132];
  __shared__ float ws[32][132];
  const int tid = threadIdx.x;
  for (int t = tid; t < 2048; t += 256) ws[t >> 7][t & 127] = wq[t];
  for (int t = tid; t < 2048; t += 256) ws[16 + (t >> 7)][t & 127] = wk[t];
  const int wv = tid >> 6, lane = tid & 63;
  const int base = blockIdx.x * TROWS;
  {
    float2 gg = ((const float2*)g)[lane];
    float2 bb = ((const float2*)b)[lane];
    // batch the 16 row loads (independent, in flight together)
    float2 vv[16];
#pragma unroll
    for (int t = 0; t < 16; ++t) {
      const int r = wv * 16 + t;
      vv[t] = ((const float2*)(x + (size_t)(base + r) * 128))[lane];
    }
    // 16 independent reduce+write chains; compiler interleaves across VALU
#pragma unroll
    for (int t = 0; t < 16; ++t) {
      const int r = wv * 16 + t;
      float2 v = vv[t];
      float s1 = v.x + v.y, s2 = v.x * v.x + v.y * v.y;
#pragma unroll
      for (int k = 1; k < 64; k <<= 1) {
        s1 += __shfl_xor(s1, k);
        s2 += __shfl_xor(s2, k);
      }
      float mean = s1 * (1.f / 128.f);
      float var = s2 * (1.f / 128.f) - mean * mean;
      float rstd = rsqrtf(var + 1e-5f);
      float y0 = (v.x - mean) * rstd * gg.x + bb.x;
      float y1 = (v.y - mean) * rstd * gg.y + bb.y;
      ((float2*)(x + (size_t)(base + r) * 128))[lane] = make_float2(y0, y1);
      ((u32*)xb)[(size_t)(base + r) * 64 + lane] = cvtpk(y0, y1);
      ys[r][2 * lane] = y0;
      ys[r][2 * lane + 1] = y1;
    }
  }
  __syncthreads();
  const int e = tid & 7;
  const int rg = tid >> 3;                 // 0..31
  const int row0 = rg * 2;
  const int pbase = base + row0;
  const int half = (pbase >= ROWS_) ? 1 : 0;   // block-uniform (64 | 28672)
  const float4* y0p = (const float4*)&ys[row0][0];
  const float4* y1p = (const float4*)&ys[row0 + 1][0];
  if (mode == 0) {
    // all four cols: {e->A, e+8->B, e+16->G, e+24->D}
    const float4* w0 = (const float4*)&ws[e][0];
    const float4* w1 = (const float4*)&ws[e + 8][0];
    const float4* w2 = (const float4*)&ws[e + 16][0];
    const float4* w3 = (const float4*)&ws[e + 24][0];
    float4 s0a = {0.f, 0.f, 0.f, 0.f}, s0b = s0a, s1a = s0a, s1b = s0a;
    float4 s2a = s0a, s2b = s0a, s3a = s0a, s3b = s0a;
#pragma unroll 4
    for (int f4 = 0; f4 < 32; ++f4) {
      float4 ya = y0p[f4], yb = y1p[f4];
      float4 wa = w0[f4], wb = w1[f4], wc = w2[f4], wd = w3[f4];
      s0a.x += ya.x * wa.x; s0a.y += ya.y * wa.y; s0a.z += ya.z * wa.z; s0a.w += ya.w * wa.w;
      s0b.x += yb.x * wa.x; s0b.y += yb.y * wa.y; s0b.z += yb.z * wa.z; s0b.w += yb.w * wa.w;
      s1a.x += ya.x * wb.x; s1a.y += ya.y * wb.y; s1a.z += ya.z * wb.z; s1a.w += ya.w * wb.w;
      s1b.x += yb.x * wb.x; s1b.y += yb.y * wb.y; s1b.z += yb.z * wb.z; s1b.w += yb.w * wb.w;
      s2a.x += ya.x * wc.x; s2a.y += ya.y * wc.y; s2a.z += ya.z * wc.z; s2a.w += ya.w * wc.w;
      s2b.x += yb.x * wc.x; s2b.y += yb.y * wc.y; s2b.z += yb.z * wc.z; s2b.w += yb.w * wc.w;
      s3a.x += ya.x * wd.x; s3a.y += ya.y * wd.y; s3a.z += ya.z * wd.z; s3a.w += ya.w * wd.w;
      s3b.x += yb.x * wd.x; s3b.y += yb.y * wd.y; s3b.z += yb.z * wd.z; s3b.w += yb.w * wd.w;
    }
    const float cadd0 = cq[e], cadd1 = cq[8 + e], cadd2 = ck[e], cadd3 = ck[8 + e];
#pragma unroll
    for (int rr = 0; rr < 2; ++rr) {
      const int ploc = pbase + rr - half * ROWS_;
      const int i = ploc >> 7, blow = ploc & 127;
      const int b_out = half * 128 + blow;
      const size_t o = (size_t)(b_out * 8 + e) * 224 + i;
      const float4 sa = rr ? s0b : s0a;
      const float4 sb = rr ? s1b : s1a;
      const float4 sc = rr ? s2b : s2a;
      const float4 sd = rr ? s3b : s3a;
      outA[o] = ((sa.x + sa.y) + (sa.z + sa.w)) + cadd0;
      outB[o] = ((sb.x + sb.y) + (sb.z + sb.w)) + cadd1;
      outG[o] = ((sc.x + sc.y) + (sc.z + sc.w)) + cadd2;
      outD[o] = ((sd.x + sd.y) + (sd.z + sd.w)) + cadd3;
    }
  } else {
    // mode 1: half==0 (xl rows) -> k-side cols {e+16->G, e+24->D};
    //         half==1 (xr rows) -> q-side cols {e->A, e+8->B}.
    const int wb0 = half ? e : e + 16;
    const int wb1 = half ? e + 8 : e + 24;
    const float4* w0 = (const float4*)&ws[wb0][0];
    const float4* w1 = (const float4*)&ws[wb1][0];
    float4 s0a = {0.f, 0.f, 0.f, 0.f}, s0b = s0a, s1a = s0a, s1b = s0a;
#pragma unroll 4
    for (int f4 = 0; f4 < 32; ++f4) {
      float4 ya = y0p[f4], yb = y1p[f4];
      float4 wa = w0[f4], wb = w1[f4];
      s0a.x += ya.x * wa.x; s0a.y += ya.y * wa.y; s0a.z += ya.z * wa.z; s0a.w += ya.w * wa.w;
      s0b.x += yb.x * wa.x; s0b.y += yb.y * wa.y; s0b.z += yb.z * wa.z; s0b.w += yb.w * wa.w;
      s1a.x += ya.x * wb.x; s1a.y += ya.y * wb.y; s1a.z += ya.z * wb.z; s1a.w += ya.w * wb.w;
      s1b.x += yb.x * wb.x; s1b.y += yb.y * wb.y; s1b.z += yb.z * wb.z; s1b.w += yb.w * wb.w;
    }
    float* d0 = half ? outA : outG;
    float* d1 = half ? outB : outD;
    const float cadd0 = half ? cq[e] : ck[e];
    const float cadd1 = half ? cq[8 + e] : ck[8 + e];
#pragma unroll
    for (int rr = 0; rr < 2; ++rr) {
      const int ploc = pbase + rr - half * ROWS_;
      const int i = ploc >> 7, blow = ploc & 127;
      const int b_out = blow;
      const size_t o = (size_t)(b_out * 8 + e) * 224 + i;
      const float4 sa = rr ? s0b : s0a;
      const float4 sb = rr ? s1b : s1a;
      d0[o] = ((sa.x + sa.y) + (sa.z + sa.w)) + cadd0;
      d1[o] = ((sb.x + sb.y) + (sb.z + sb.w)) + cadd1;
    }
  }
}

// ---------------------------------------------------------------------------
// Plain 64x64-tile bf16 MFMA GEMM (bf16 A input) — R3-verified version.
// mode 4: fout += acc + bias (out-proj residual); mode 5: fout = acc + bias.
// ---------------------------------------------------------------------------
__global__ __launch_bounds__(256) void gemm_plain(
    const u16* __restrict__ A, const u16* __restrict__ B,
    const float* __restrict__ bias, int mode, float* __restrict__ fout) {
  __shared__ u16 As[64 * 136];
  __shared__ u16 Bs[64 * 136];
  const int tid = threadIdx.x;
  const int M0 = blockIdx.x * 64, N0 = blockIdx.y * 64;
  const uint4* Ag = (const uint4*)(A + (size_t)M0 * 128);
  const uint4* Bg = (const uint4*)(B + (size_t)N0 * 128);
  for (int t = tid; t < 1024; t += 256) {
    int row = t >> 4, cc = t & 15;
    *(uint4*)&As[row * 136 + cc * 8] = Ag[row * 16 + cc];
  }
  for (int t = tid; t < 1024; t += 256) {
    int row = t >> 4, cc = t & 15;
    *(uint4*)&Bs[row * 136 + cc * 8] = Bg[row * 16 + cc];
  }
  __syncthreads();
  const int wave = tid >> 6, lane = tid & 63;
  const int wm = (wave >> 1) * 32, wn = (wave & 1) * 32;
  const int lr = lane & 15, kq = (lane >> 4) * 8;
  f32x4 acc[2][2] = {};
#pragma unroll
  for (int ks = 0; ks < 4; ++ks) {
    int ko = ks * 32 + kq;
    bf16x8 a0 = *(const bf16x8*)&As[(wm + lr) * 136 + ko];
    bf16x8 a1 = *(const bf16x8*)&As[(wm + 16 + lr) * 136 + ko];
    bf16x8 b0 = *(const bf16x8*)&Bs[(wn + lr) * 136 + ko];
    bf16x8 b1 = *(const bf16x8*)&Bs[(wn + 16 + lr) * 136 + ko];
    acc[0][0] = __builtin_amdgcn_mfma_f32_16x16x32_bf16(a0, b0, acc[0][0], 0, 0, 0);
    acc[0][1] = __builtin_amdgcn_mfma_f32_16x16x32_bf16(a0, b1, acc[0][1], 0, 0, 0);
    acc[1][0] = __builtin_amdgcn_mfma_f32_16x16x32_bf16(a1, b0, acc[1][0], 0, 0, 0);
    acc[1][1] = __builtin_amdgcn_mfma_f32_16x16x32_bf16(a1, b1, acc[1][1], 0, 0, 0);
  }
  const int colq = lane & 15, rowq = (lane >> 4) * 4;
#pragma unroll
  for (int tm = 0; tm < 2; ++tm)
#pragma unroll
    for (int tn = 0; tn < 2; ++tn) {
#pragma unroll
      for (int r = 0; r < 4; ++r) {
        int row = M0 + wm + tm * 16 + rowq + r;
        int col = N0 + wn + tn * 16 + colq;
        float v = acc[tm][tn][r] + bias[col];
        if (mode == 4) fout[(size_t)row * 128 + col] += v;
        else           fout[(size_t)row * 128 + col] = v;
      }
    }
}

// ---------------------------------------------------------------------------
// Self QKV GEMM: 128x128 tiles, 512 threads (8 waves, each 64x32). A from XB.
// ---------------------------------------------------------------------------
__global__ __launch_bounds__(512) void gemm_qkv_self(
    const u16* __restrict__ X, const u16* __restrict__ Bw,
    const float* __restrict__ bias, u16* __restrict__ o0, u16* __restrict__ o1,
    u16* __restrict__ o2) {
  __shared__ u16 As[128 * 136];
  __shared__ u16 Bs[128 * 136];
  const int tid = threadIdx.x;
  const int M0 = blockIdx.x * 128, N0 = blockIdx.y * 128;
  {
    const uint4* Bg = (const uint4*)(Bw + (size_t)N0 * 128);
    const uint4* Ag = (const uint4*)(X + (size_t)M0 * 128);
    for (int t = tid; t < 2048; t += 512) {
      int row = t >> 4, cc = t & 15;
      *(uint4*)&As[row * 136 + cc * 8] = Ag[row * 16 + cc];
      *(uint4*)&Bs[row * 136 + cc * 8] = Bg[row * 16 + cc];
    }
  }
  __syncthreads();
  const int wave = tid >> 6, lane = tid & 63;
  const int wm = (wave >> 2) * 64, wn = (wave & 3) * 32;
  const int lr = lane & 15, kq = (lane >> 4) * 8;
  f32x4 acc[4][2] = {};
#pragma unroll
  for (int ks = 0; ks < 4; ++ks) {
    int ko = ks * 32 + kq;
    bf16x8 b0 = *(const bf16x8*)&Bs[(wn + lr) * 136 + ko];
    bf16x8 b1 = *(const bf16x8*)&Bs[(wn + 16 + lr) * 136 + ko];
#pragma unroll
    for (int tm = 0; tm < 4; ++tm) {
      bf16x8 a0 = *(const bf16x8*)&As[(wm + tm * 16 + lr) * 136 + ko];
      acc[tm][0] = __builtin_amdgcn_mfma_f32_16x16x32_bf16(a0, b0, acc[tm][0], 0, 0, 0);
      acc[tm][1] = __builtin_amdgcn_mfma_f32_16x16x32_bf16(a0, b1, acc[tm][1], 0, 0, 0);
    }
  }
  const int colq = lane & 15, rowq = (lane >> 4) * 4;
#pragma unroll
  for (int tm = 0; tm < 4; ++tm)
#pragma unroll
    for (int tn = 0; tn < 2; ++tn) {
#pragma unroll
      for (int r = 0; r < 4; ++r) {
        int row = M0 + wm + tm * 16 + rowq + r;
        int col = N0 + wn + tn * 16 + colq;
        float v = acc[tm][tn][r] + bias[col];
        int part = col >> 7;
        int cc = col & 127;
        int e = cc >> 4, c = cc & 15;
        int rloc = row, badd = 0;
        if (row >= ROWS_) { rloc = row - ROWS_; badd = 128; }
        int b = (rloc & 127) + badd, pos = rloc >> 7;
        size_t off = ((size_t)(b * NH + e) * W_ + pos) * HD + c;
        if (part == 0)      o0[off] = f2bf(v * 0.25f);
        else if (part == 1) o1[off] = f2bf(v);
        else                o2[off] = f2bf(v);
      }
    }
}

// ---------------------------------------------------------------------------
// Cross QKV GEMM: 128x128 tiles, 512 threads.
// y=0: q from Xr (*0.25); y=1: K from Xl; y=2: V from Xl.
// At l=5 launched with grid.y=2 (V dead: no attn launch, corresp reads Q/K).
// ---------------------------------------------------------------------------
__global__ __launch_bounds__(512) void gemm_qkv_cross(
    const u16* __restrict__ Xl, const u16* __restrict__ Xr,
    const u16* __restrict__ cWi, const float* __restrict__ cbi,
    u16* __restrict__ QB, u16* __restrict__ KB, u16* __restrict__ VB) {
  __shared__ u16 As[128 * 136];
  __shared__ u16 Bs[128 * 136];
  const int tid = threadIdx.x;
  const int M0 = blockIdx.x * 128;
  const int y = blockIdx.y;
  const u16* X = (y == 0) ? Xr : Xl;
  const u16* Bw = cWi + (size_t)y * 128 * 128;
  const float* bias = cbi + y * 128;
  {
    const uint4* Bg = (const uint4*)Bw;
    const uint4* Ag = (const uint4*)(X + (size_t)M0 * 128);
    for (int t = tid; t < 2048; t += 512) {
      int row = t >> 4, cc = t & 15;
      *(uint4*)&As[row * 136 + cc * 8] = Ag[row * 16 + cc];
      *(uint4*)&Bs[row * 136 + cc * 8] = Bg[row * 16 + cc];
    }
  }
  __syncthreads();
  const int wave = tid >> 6, lane = tid & 63;
  const int wm = (wave >> 2) * 64, wn = (wave & 3) * 32;
  const int lr = lane & 15, kq = (lane >> 4) * 8;
  f32x4 acc[4][2] = {};
#pragma unroll
  for (int ks = 0; ks < 4; ++ks) {
    int ko = ks * 32 + kq;
    bf16x8 b0 = *(const bf16x8*)&Bs[(wn + lr) * 136 + ko];
    bf16x8 b1 = *(const bf16x8*)&Bs[(wn + 16 + lr) * 136 + ko];
#pragma unroll
    for (int tm = 0; tm < 4; ++tm) {
      bf16x8 a0 = *(const bf16x8*)&As[(wm + tm * 16 + lr) * 136 + ko];
      acc[tm][0] = __builtin_amdgcn_mfma_f32_16x16x32_bf16(a0, b0, acc[tm][0], 0, 0, 0);
      acc[tm][1] = __builtin_amdgcn_mfma_f32_16x16x32_bf16(a0, b1, acc[tm][1], 0, 0, 0);
    }
  }
  u16* outp = (y == 0) ? QB : ((y == 1) ? KB : VB);
  const float scale = (y == 0) ? 0.25f : 1.f;
  const int colq = lane & 15, rowq = (lane >> 4) * 4;
#pragma unroll
  for (int tm = 0; tm < 4; ++tm)
#pragma unroll
    for (int tn = 0; tn < 2; ++tn) {
#pragma unroll
      for (int r = 0; r < 4; ++r) {
        int row = M0 + wm + tm * 16 + rowq + r;
        int col = wn + tn * 16 + colq;
        float v = (acc[tm][tn][r] + bias[col]) * scale;
        int e = col >> 4, c = col & 15;
        int b = row & 127, pos = row >> 7;
        outp[((size_t)(b * NH + e) * W_ + pos) * HD + c] = f2bf(v);
      }
    }
}

// ---------------------------------------------------------------------------
// MFMA flash attention per (head e, batch-row b). Two-pass softmax. P stays
// in registers (sigma-permuted V); exp2 with log2e folded into Q-side staging.
// ---------------------------------------------------------------------------
__global__ __launch_bounds__(448) void attn_kernel(
    const u16* __restrict__ qb, const u16* __restrict__ kb,
    const u16* __restrict__ vb, const float* __restrict__ ALPHA,
    const float* __restrict__ BETA, const float* __restrict__ GAMMA,
    const float* __restrict__ DELTA, u16* __restrict__ obuf) {
  __shared__ u16 Ksh[224 * KSTR];
  __shared__ u16 Qsh[224 * KSTR];
  __shared__ u16 Vt[16 * VSTR];
  const int e = blockIdx.x, b = blockIdx.y;
  const size_t hb = (size_t)(b * NH + e);
  const int tid = threadIdx.x;
  const u32 ONE = 0x3F80u;
  const float LOG2E = 1.4426950408889634f;

  if (tid < 224) {
    const int j = tid;
    const uint4* src = (const uint4*)(kb + (hb * W_ + j) * HD);
    uint4 a = src[0], b2 = src[1];
    *(uint4*)&Ksh[j * KSTR] = a;
    *(uint4*)&Ksh[j * KSTR + 8] = b2;
    float G = GAMMA[hb * 224 + j];
    float D = DELTA[hb * 224 + j];
    float jf = (float)j;
    float P = (G * jf + D) * LOG2E;
    u16 Phi = f2bf(P);
    float Plo = P - __uint_as_float((u32)Phi << 16);
    u32* ex = (u32*)&Ksh[j * KSTR + 16];
    ex[0] = (u32)f2bf(G * LOG2E) | ((u32)Phi << 16);
    ex[1] = (u32)f2bf(Plo) | ((u32)f2bf(jf) << 16);
    ex[2] = ONE | (ONE << 16);
#pragma unroll
    for (int z = 3; z < 12; ++z) ex[z] = 0;
    const uint4* vsrc = (const uint4*)(vb + (hb * W_ + j) * HD);
    uint4 va = vsrc[0], vb4 = vsrc[1];
    u32 w[8] = {va.x, va.y, va.z, va.w, vb4.x, vb4.y, vb4.z, vb4.w};
    // sigma-permuted column so PV A-fragments come straight from registers
    const int jl = j & 31;
    const int qcol = (j & ~31) | (((jl >> 2) & 3) << 3) | ((jl >> 4) << 2) | (jl & 3);
#pragma unroll
    for (int c = 0; c < 16; ++c)
      Vt[c * VSTR + qcol] = (c & 1) ? (u16)(w[c >> 1] >> 16) : (u16)(w[c >> 1] & 0xFFFF);
  } else {
    const int i = tid - 224;
    const uint4* src = (const uint4*)(qb + (hb * W_ + i) * HD);
    uint4 a = src[0], b2 = src[1];
    u32 qa[8] = {a.x, a.y, a.z, a.w, b2.x, b2.y, b2.z, b2.w};
#pragma unroll
    for (int t = 0; t < 8; ++t)
      qa[t] = cvtpk(bflo(qa[t]) * LOG2E, bfhi(qa[t]) * LOG2E);
    *(uint4*)&Qsh[i * KSTR] = make_uint4(qa[0], qa[1], qa[2], qa[3]);
    *(uint4*)&Qsh[i * KSTR + 8] = make_uint4(qa[4], qa[5], qa[6], qa[7]);
    float al = ALPHA[hb * 224 + i];
    float be = BETA[hb * 224 + i];
    float ifl = (float)i;
    float Q = (be - al * ifl) * LOG2E;
    u16 Qhi = f2bf(Q);
    float Qlo = Q - __uint_as_float((u32)Qhi << 16);
    u32* ex = (u32*)&Qsh[i * KSTR + 16];
    ex[0] = (u32)f2bf(-ifl) | (ONE << 16);
    ex[1] = ONE | ((u32)f2bf(al * LOG2E) << 16);
    ex[2] = (u32)Qhi | ((u32)f2bf(Qlo) << 16);
#pragma unroll
    for (int z = 3; z < 12; ++z) ex[z] = 0;
  }
  __syncthreads();

  const int wid = tid >> 6, lane = tid & 63;
  const int g = lane >> 4, li = lane & 15;
  const int obase = (b & 128) ? ROWS_ : 0;
  const int blow = b & 127;

  for (int qt = wid * 2; qt < wid * 2 + 2; ++qt) {
    const int i0 = qt * 16;
    const bf16x8 Bq = *(const bf16x8*)&Qsh[(i0 + li) * KSTR + g * 8];
    f32x4 C[7][2];
#pragma unroll
    for (int js = 0; js < 7; ++js) {
      const bf16x8 A0 = *(const bf16x8*)&Ksh[(js * 32 + li) * KSTR + g * 8];
      const bf16x8 A1 = *(const bf16x8*)&Ksh[(js * 32 + 16 + li) * KSTR + g * 8];
      const f32x4 Z = {0.f, 0.f, 0.f, 0.f};
      C[js][0] = __builtin_amdgcn_mfma_f32_16x16x32_bf16(A0, Bq, Z, 0, 0, 0);
      C[js][1] = __builtin_amdgcn_mfma_f32_16x16x32_bf16(A1, Bq, Z, 0, 0, 0);
    }
    float m = -1e30f;
#pragma unroll
    for (int js = 0; js < 7; ++js)
#pragma unroll
      for (int h = 0; h < 2; ++h)
        m = fmaxf(m, fmaxf(fmaxf(C[js][h][0], C[js][h][1]), fmaxf(C[js][h][2], C[js][h][3])));
    m = fmaxf(m, __shfl_xor(m, 16));
    m = fmaxf(m, __shfl_xor(m, 32));
    f32x4 O = {0.f, 0.f, 0.f, 0.f};
    float lsum = 0.f;
#pragma unroll
    for (int js = 0; js < 7; ++js) {
      float p0 = EX2(C[js][0][0] - m), p1 = EX2(C[js][0][1] - m);
      float p2 = EX2(C[js][0][2] - m), p3 = EX2(C[js][0][3] - m);
      float p4 = EX2(C[js][1][0] - m), p5 = EX2(C[js][1][1] - m);
      float p6 = EX2(C[js][1][2] - m), p7 = EX2(C[js][1][3] - m);
      lsum += ((p0 + p1) + (p2 + p3)) + ((p4 + p5) + (p6 + p7));
      uint4 pu = make_uint4(cvtpk(p0, p1), cvtpk(p2, p3), cvtpk(p4, p5), cvtpk(p6, p7));
      const bf16x8 Ap = __builtin_bit_cast(bf16x8, pu);
      const bf16x8 Bv = *(const bf16x8*)&Vt[li * VSTR + js * 32 + g * 8];
      O = __builtin_amdgcn_mfma_f32_16x16x32_bf16(Ap, Bv, O, 0, 0, 0);
    }
    lsum += __shfl_xor(lsum, 16);
    lsum += __shfl_xor(lsum, 32);
#pragma unroll
    for (int r = 0; r < 4; ++r) {
      const float lr = __shfl(lsum, g * 4 + r);
      const int irow = i0 + g * 4 + r;
      obuf[((size_t)(obase + irow * 128 + blow)) * C_ + e * HD + li] = f2bf(O[r] * (1.f / lr));
    }
  }
}

// Gather x_l/x_r[b][c][h][w] -> bf16 rows p = img*28672 + w*128 + h*2 + b.
__global__ __launch_bounds__(256) void transpose_kernel(const float* __restrict__ x_l,
                                                        const float* __restrict__ x_r,
                                                        u16* __restrict__ xT) {
  __shared__ float tile[128][57];
  const int wt = blockIdx.x * 56, hi = blockIdx.y;
  const int img = blockIdx.z >> 1, bi = blockIdx.z & 1;
  const float* x = img ? x_r : x_l;
  const int wave = threadIdx.x >> 6, lane = threadIdx.x & 63;
  for (int c = wave; c < 128; c += 4) {
    if (lane < 56)
      tile[c][lane] = x[(((size_t)bi * 128 + c) * 64 + hi) * 224 + wt + lane];
  }
  __syncthreads();
  u32* dst = (u32*)xT;
  for (int w = wave; w < 56; w += 4) {
    int p = img * ROWS_ + (wt + w) * 128 + hi * 2 + bi;
    float a = tile[lane * 2][w], b2 = tile[lane * 2 + 1][w];
    dst[(size_t)p * 64 + lane] = (u32)f2bf(a) | ((u32)f2bf(b2) << 16);
  }
}

// ---------------------------------------------------------------------------
// Final soft-argmax, MFMA version.
// ---------------------------------------------------------------------------
__global__ __launch_bounds__(448) void corresp_kernel(
    const u16* __restrict__ qb, const u16* __restrict__ kb,
    const float* __restrict__ ALPHA, const float* __restrict__ BETA,
    const float* __restrict__ GAMMA, const float* __restrict__ DELTA,
    float* __restrict__ out) {
  __shared__ u16 Ksh[224 * 136];   // 60,928 B
  __shared__ float Gs[224], Ds[224];
  const int b = blockIdx.x, tid = threadIdx.x;
  if (tid < 224) {
    const int j = tid;
#pragma unroll
    for (int e = 0; e < 8; ++e) {
      const uint4* src = (const uint4*)(kb + ((size_t)(b * 8 + e) * 224 + j) * 16);
      *(uint4*)&Ksh[j * 136 + e * 16] = src[0];
      *(uint4*)&Ksh[j * 136 + e * 16 + 8] = src[1];
    }
    float gs = 0.f, ds = 0.f;
#pragma unroll
    for (int e = 0; e < 8; ++e) {
      gs += GAMMA[((size_t)(b * 8 + e)) * 224 + j];
      ds += DELTA[((size_t)(b * 8 + e)) * 224 + j];
    }
    Gs[j] = gs;
    Ds[j] = ds;
  }
  __syncthreads();
  const int wid = tid >> 6, lane = tid & 63;
  const int g = lane >> 4, li = lane & 15;
  const int i = blockIdx.y * 112 + wid * 16 + li;
  bf16x8 Bq[4];
#pragma unroll
  for (int ks = 0; ks < 4; ++ks) {
    const int e2 = ks * 2 + (g >> 1), c0 = (g & 1) * 8;
    Bq[ks] = *(const bf16x8*)&qb[((size_t)(b * 8 + e2) * 224 + i) * 16 + c0];
  }
  f32x4 C[14];
#pragma unroll
  for (int js = 0; js < 14; ++js) {
    f32x4 acc = {0.f, 0.f, 0.f, 0.f};
#pragma unroll
    for (int ks = 0; ks < 4; ++ks) {
      const bf16x8 A = *(const bf16x8*)&Ksh[(js * 16 + li) * 136 + ks * 32 + g * 8];
      acc = __builtin_amdgcn_mfma_f32_16x16x32_bf16(A, Bq[ks], acc, 0, 0, 0);
    }
    C[js] = acc;
  }
  float ai = 0.f, bi_ = 0.f;
#pragma unroll
  for (int e = 0; e < 8; ++e) {
    ai += ALPHA[((size_t)(b * 8 + e)) * 224 + i];
    bi_ += BETA[((size_t)(b * 8 + e)) * 224 + i];
  }
  const float ifl = (float)i;
  float m = -1e30f;
#pragma unroll
  for (int js = 0; js < 14; ++js) {
#pragma unroll
    for (int r = 0; r < 4; ++r) {
      const int j = js * 16 + g * 4 + r;
      float s = C[js][r] + ((float)j - ifl) * (ai + Gs[j]) + bi_ + Ds[j];
      C[js][r] = s;
      m = fmaxf(m, s);
    }
  }
  m = fmaxf(m, __shfl_xor(m, 16));
  m = fmaxf(m, __shfl_xor(m, 32));
  float l = 0.f, wj = 0.f;
#pragma unroll
  for (int js = 0; js < 14; ++js) {
#pragma unroll
    for (int r = 0; r < 4; ++r) {
      const float p = __expf(C[js][r] - m);
      l += p;
      wj += p * (float)(js * 16 + g * 4 + r);
    }
  }
  l += __shfl_xor(l, 16);
  l += __shfl_xor(l, 32);
  wj += __shfl_xor(wj, 16);
  wj += __shfl_xor(wj, 32);
  if (g == 0) out[(size_t)b * 224 + i] = ifl - wj / fmaxf(l, 1e-30f);
}

// Single-launch conversion of all five weight tensors to one bf16 buffer.
#define OFF_FEAT 0
#define OFF_SWI 16384
#define OFF_SWO 311296
#define OFF_CWI 409600
#define OFF_CWO 704512
#define N_WALL 802816
__global__ __launch_bounds__(256) void cvt_all_kernel(
    const float* __restrict__ feat_w, const float* __restrict__ self_Wi,
    const float* __restrict__ self_Wo, const float* __restrict__ cross_Wi,
    const float* __restrict__ cross_Wo, u16* __restrict__ dst) {
  int idx = blockIdx.x * 256 + threadIdx.x;
  if (idx >= N_WALL) return;
  float v;
  if (idx < OFF_SWI)       v = feat_w[idx];
  else if (idx < OFF_SWO)  v = self_Wi[idx - OFF_SWI];
  else if (idx < OFF_CWI)  v = self_Wo[idx - OFF_SWO];
  else if (idx < OFF_CWO)  v = cross_Wi[idx - OFF_CWI];
  else                     v = cross_Wo[idx - OFF_CWO];
  dst[idx] = f2bf(v);
}

extern "C" void kernel_launch(void* const* d_in, const int* in_sizes, int n_in,
                              void* d_out, int out_size, void* d_ws, size_t ws_size,
                              hipStream_t stream) {
  (void)in_sizes; (void)n_in; (void)out_size; (void)ws_size;
  const float* x_l = (const float*)d_in[0];
  const float* x_r = (const float*)d_in[1];
  const float* feat_w = (const float*)d_in[2];
  const float* feat_b = (const float*)d_in[3];
  const float* self_Wi = (const float*)d_in[4];
  const float* self_bi = (const float*)d_in[5];
  const float* self_Wo = (const float*)d_in[6];
  const float* self_bo = (const float*)d_in[7];
  const float* cross_Wi = (const float*)d_in[8];
  const float* cross_bi = (const float*)d_in[9];
  const float* cross_Wo = (const float*)d_in[10];
  const float* cross_bo = (const float*)d_in[11];
  const float* ln_g = (const float*)d_in[12];
  const float* ln_b = (const float*)d_in[13];

  char* ws = (char*)d_ws;
  size_t off = 0;
  auto alloc = [&](size_t bytes) {
    char* p = ws + off;
    off += (bytes + 255) & ~(size_t)255;
    return p;
  };
  // Total ~97 MB — under the R6-proven ~112 MB budget. XB aliases OB:
  // XB live range is tab->qkv, OB live range is attn->out-proj (disjoint).
  float* XA = (float*)alloc((size_t)2 * ROWS_ * C_ * 4);   // residual (in-place LN)
  u16* QB = (u16*)alloc((size_t)256 * NH * W_ * HD * 2);   // also XT scratch
  u16* KB = (u16*)alloc((size_t)256 * NH * W_ * HD * 2);
  u16* VB = (u16*)alloc((size_t)256 * NH * W_ * HD * 2);
  u16* OB = (u16*)alloc((size_t)2 * ROWS_ * C_ * 2);
  u16* WALL = (u16*)alloc((size_t)N_WALL * 2);
  float* PREP = (float*)alloc((size_t)12 * PREP_STRIDE * 4);
  float* ALPHA = (float*)alloc((size_t)256 * NH * W_ * 4);
  float* BETA = (float*)alloc((size_t)256 * NH * W_ * 4);
  float* GAMMA = (float*)alloc((size_t)256 * NH * W_ * 4);
  float* DELTA = (float*)alloc((size_t)256 * NH * W_ * 4);
  u16* XB = OB;   // alias — disjoint live ranges

  cvt_all_kernel<<<3136, 256, 0, stream>>>(feat_w, self_Wi, self_Wo, cross_Wi, cross_Wo, WALL);
  prep_kernel<<<dim3(12, 8), 256, 0, stream>>>(self_Wi, self_bi, cross_Wi, cross_bi, PREP);

  transpose_kernel<<<dim3(4, 64, 4), 256, 0, stream>>>(x_l, x_r, QB);
  gemm_plain<<<dim3(896, 2), 256, 0, stream>>>(QB, WALL + OFF_FEAT, feat_b, 5, XA);

  for (int l = 0; l < 6; ++l) {
    const u16* sWi = WALL + OFF_SWI + (size_t)l * 384 * 128;
    const u16* sWo = WALL + OFF_SWO + (size_t)l * 128 * 128;
    const u16* cWi = WALL + OFF_CWI + (size_t)l * 384 * 128;
    const u16* cWo = WALL + OFF_CWO + (size_t)l * 128 * 128;
    const float* sbi = self_bi + l * 384;
    const float* sbo = self_bo + l * 128;
    const float* cbi = cross_bi + l * 384;
    const float* cbo = cross_bo + l * 128;
    const float* ps = PREP + (size_t)(l * 2) * PREP_STRIDE;
    const float* pc = PREP + (size_t)(l * 2 + 1) * PREP_STRIDE;

    // --- self attention on xl AND xr: X = LN(X) (+tables+XB), qkv, attn, +=proj ---
    tab_kernel<<<896, 256, 0, stream>>>(XA, ln_g, ln_b, ps, ps + 4096, ALPHA, BETA,
                                        ps + 2048, ps + 4112, GAMMA, DELTA, XB, 0);
    gemm_qkv_self<<<dim3(448, 3), 512, 0, stream>>>(XB, sWi, sbi, QB, KB, VB);
    attn_kernel<<<dim3(8, 256), 448, 0, stream>>>(QB, KB, VB, ALPHA, BETA, GAMMA, DELTA, OB);
    gemm_plain<<<dim3(896, 2), 256, 0, stream>>>(OB, sWo, sbo, 4, XA);

    // --- cross attention: q from xr, k/v from xl; X = LN(X) first ---
    tab_kernel<<<896, 256, 0, stream>>>(XA, ln_g, ln_b, pc, pc + 4096, ALPHA, BETA,
                                        pc + 2048, pc + 4112, GAMMA, DELTA, XB, 1);
    // l==5: V (y=2) is dead — no attn launch follows and corresp reads QB/KB only.
    gemm_qkv_cross<<<dim3(224, (l < 5) ? 3 : 2), 512, 0, stream>>>(
        XB, XB + (size_t)ROWS_ * C_, cWi, cbi, QB, KB, VB);
    if (l < 5) {
      attn_kernel<<<dim3(8, 128), 448, 0, stream>>>(QB, KB, VB, ALPHA, BETA, GAMMA, DELTA, OB);
      gemm_plain<<<dim3(448, 2), 256, 0, stream>>>(OB, cWo, cbo, 4, XA);  // xl half only
    }
    // l == 5: attention output / x updates dead; corresp reads QB/KB + tables.
  }
  corresp_kernel<<<dim3(128, 2), 448, 0, stream>>>(QB, KB, ALPHA, BETA, GAMMA, DELTA,
                                                   (float*)d_out);
}

// Round 12
// 1150.827 us; speedup vs baseline: 1.0104x; 1.0104x over previous
//
#include <hip/hip_runtime.h>

typedef unsigned short u16;
typedef unsigned int u32;

#define W_ 224
#define H_ 128
#define C_ 128
#define NH 8
#define HD 16
#define ROWS_ (W_ * H_)          // 28672 rows per image
#define PREP_STRIDE 4128
#define KSTR 40
#define VSTR 232
#define TROWS 32                 // rows per tab_kernel block (R12: revert to 32)

typedef __bf16 bf16x8 __attribute__((ext_vector_type(8)));
typedef float f32x4 __attribute__((ext_vector_type(4)));

__device__ __forceinline__ u16 f2bf(float f) {
  u32 u = __float_as_uint(f);
  return (u16)((u + 0x7FFFu + ((u >> 16) & 1u)) >> 16);
}
// Packed RNE f32->bf16 pair: single v_cvt_pk_bf16_f32 (same rounding as f2bf).
__device__ __forceinline__ u32 cvtpk(float lo, float hi) {
  u32 r;
  asm("v_cvt_pk_bf16_f32 %0, %1, %2" : "=v"(r) : "v"(lo), "v"(hi));
  return r;
}
__device__ __forceinline__ float bflo(u32 u) { return __uint_as_float(u << 16); }
__device__ __forceinline__ float bfhi(u32 u) { return __uint_as_float(u & 0xFFFF0000u); }

#if __has_builtin(__builtin_amdgcn_exp2f)
#define EX2(x) __builtin_amdgcn_exp2f(x)
#else
#define EX2(x) __expf((x) * 0.6931471805599453f)
#endif

// ---------------------------------------------------------------------------
// Rank-1 PE decomposition prep: grid (12 s, 8 e-groups), LDS-staged, coalesced.
// ---------------------------------------------------------------------------
__global__ __launch_bounds__(256) void prep_kernel(
    const float* __restrict__ self_Wi, const float* __restrict__ self_bi,
    const float* __restrict__ cross_Wi, const float* __restrict__ cross_bi,
    float* __restrict__ prep) {
  __shared__ float Wq[16][132];
  __shared__ float Wk[16][132];
  __shared__ float u[128];
  __shared__ float Aq[16], Ak[16], bq[16], bk[16];
  const int s = blockIdx.x, e = blockIdx.y, l = s >> 1;
  const float* Wi = (s & 1) ? cross_Wi + (size_t)l * 384 * 128 : self_Wi + (size_t)l * 384 * 128;
  const float* bi = (s & 1) ? cross_bi + l * 384 : self_bi + l * 384;
  const int tid = threadIdx.x;
  if (tid < 128) {
    float ex = (float)(tid & ~1) * (1.f / 128.f);
    u[tid] = expf(-ex * logf(10000.f));
  }
  if (tid >= 128 && tid < 144) { int r = tid - 128; bq[r] = bi[e * 16 + r]; }
  if (tid >= 160 && tid < 176) { int r = tid - 160; bk[r] = bi[128 + e * 16 + r]; }
  for (int t = tid; t < 2048; t += 256) {
    int r = t >> 7, f = t & 127;
    Wq[r][f] = Wi[(size_t)(e * 16 + r) * 128 + f];
    Wk[r][f] = Wi[(size_t)(128 + e * 16 + r) * 128 + f];
  }
  __syncthreads();
  {
    const int grp = tid >> 3;
    const int lg = tid & 7;
    const float* row = (grp < 16) ? Wq[grp] : Wk[grp - 16];
    float a = 0.f;
#pragma unroll
    for (int i = 0; i < 16; ++i) a += row[lg * 16 + i] * u[lg * 16 + i];
    a += __shfl_xor(a, 1);
    a += __shfl_xor(a, 2);
    a += __shfl_xor(a, 4);
    if (lg == 0) {
      if (grp < 16) Aq[grp] = a;
      else          Ak[grp - 16] = a;
    }
  }
  __syncthreads();
  float* out = prep + (size_t)s * PREP_STRIDE;
  for (int t = tid; t < 512; t += 256) {
    int v = t >> 7, f = t & 127;
    float acc = 0.f;
#pragma unroll
    for (int c = 0; c < 16; ++c) {
      if (v == 0)      acc += Wq[c][f] * Ak[c];
      else if (v == 1) acc += Wq[c][f] * bk[c];
      else if (v == 2) acc += Wk[c][f] * Aq[c];
      else             acc += Wk[c][f] * bq[c];
    }
    out[v * 1024 + e * 128 + f] = acc * 0.25f;
  }
  if (tid < 4) {
    int v = tid;
    float acc = 0.f;
#pragma unroll
    for (int c = 0; c < 16; ++c) {
      if (v == 0)      acc += bq[c] * Ak[c];
      else if (v == 1) acc += bq[c] * bk[c];
      else if (v == 2) acc += bk[c] * Aq[c];
      else             acc += bk[c] * bq[c];
    }
    out[4096 + v * 8 + e] = acc * 0.25f;
  }
}

// ---------------------------------------------------------------------------
// Fused LN + affine-PE tables, 32 rows per block (R10-verified 1143.7us).
// R11's TROWS=64/2x4 map regressed +19us: LDS 34->51KB cut occupancy 4->3
// blocks/CU and doubled register pressure — the -25% LDS-issue win didn't
// survive the -25% wave loss. Lesson: read-count model needs occupancy term.
// Phase-2: 2x2 map, thread (c2=tid&15, rg2=tid>>4) owns cols {2c2,2c2+1},
// rows {2rg2,2rg2+1}; 128 b128 reads per 4 outputs; tables bit-identical.
// ---------------------------------------------------------------------------
__global__ __launch_bounds__(256) void tab_kernel(
    float* __restrict__ x, const float* __restrict__ g,
    const float* __restrict__ b, const float* __restrict__ wq,
    const float* __restrict__ cq, float* __restrict__ outA, float* __restrict__ outB,
    const float* __restrict__ wk, const float* __restrict__ ck,
    float* __restrict__ outG, float* __restrict__ outD,
    u16* __restrict__ xb, int mode) {
  __shared__ float ys[TROWS][132];
  __shared__ float ws[32][132];
  const int tid = threadIdx.x;
  for (int t = tid; t < 2048; t += 256) ws[t >> 7][t & 127] = wq[t];
  for (int t = tid; t < 2048; t += 256) ws[16 + (t >> 7)][t & 127] = wk[t];
  const int wv = tid >> 6, lane = tid & 63;
  const int base = blockIdx.x * TROWS;
  {
    float2 gg = ((const float2*)g)[lane];
    float2 bb = ((const float2*)b)[lane];
    // batch the 8 row loads (independent, in flight together)
    float2 vv[8];
#pragma unroll
    for (int t = 0; t < 8; ++t) {
      const int r = wv * 8 + t;
      vv[t] = ((const float2*)(x + (size_t)(base + r) * 128))[lane];
    }
    // 8 independent reduce+write chains; compiler interleaves across VALU
#pragma unroll
    for (int t = 0; t < 8; ++t) {
      const int r = wv * 8 + t;
      float2 v = vv[t];
      float s1 = v.x + v.y, s2 = v.x * v.x + v.y * v.y;
#pragma unroll
      for (int k = 1; k < 64; k <<= 1) {
        s1 += __shfl_xor(s1, k);
        s2 += __shfl_xor(s2, k);
      }
      float mean = s1 * (1.f / 128.f);
      float var = s2 * (1.f / 128.f) - mean * mean;
      float rstd = rsqrtf(var + 1e-5f);
      float y0 = (v.x - mean) * rstd * gg.x + bb.x;
      float y1 = (v.y - mean) * rstd * gg.y + bb.y;
      ((float2*)(x + (size_t)(base + r) * 128))[lane] = make_float2(y0, y1);
      ((u32*)xb)[(size_t)(base + r) * 64 + lane] = cvtpk(y0, y1);
      ys[r][2 * lane] = y0;
      ys[r][2 * lane + 1] = y1;
    }
  }
  __syncthreads();
  // 2x2 remap: thread (c2 = tid&15, rg2 = tid>>4) owns cols {2c2,2c2+1},
  // rows {2rg2, 2rg2+1}. 16x16 threads cover 32x32 outputs.
  const int c2 = tid & 15;
  const int rg2 = tid >> 4;
  const int c0 = c2 * 2;
  const int row0 = rg2 * 2;
  const int side = c0 >> 4;              // same for both cols (even start)
  const int val = (c0 & 15) >> 3;        // same for both cols
  const int e0 = c0 & 7, e1 = (c0 + 1) & 7;
  const float cadd0 = side ? ck[val * 8 + e0] : cq[val * 8 + e0];
  const float cadd1 = side ? ck[val * 8 + e1] : cq[val * 8 + e1];
  float* dst = side ? (val ? outD : outG) : (val ? outB : outA);
  // rows never straddle ROWS_ (28672 = 896*32): half uniform per block
  const int pbase = base + row0;
  const int half = (pbase >= ROWS_) ? 1 : 0;
  const bool active = (mode == 0) || (half ? (side == 0) : (side == 1));
  if (active) {
    const float4* w0 = (const float4*)&ws[c0][0];
    const float4* w1 = (const float4*)&ws[c0 + 1][0];
    const float4* y0 = (const float4*)&ys[row0][0];
    const float4* y1 = (const float4*)&ys[row0 + 1][0];
    float4 s00 = {0.f, 0.f, 0.f, 0.f}, s01 = s00, s10 = s00, s11 = s00;
#pragma unroll 4
    for (int f4 = 0; f4 < 32; ++f4) {
      float4 wa = w0[f4], wb = w1[f4];
      float4 ya = y0[f4], yb = y1[f4];
      s00.x += ya.x * wa.x; s00.y += ya.y * wa.y; s00.z += ya.z * wa.z; s00.w += ya.w * wa.w;
      s01.x += ya.x * wb.x; s01.y += ya.y * wb.y; s01.z += ya.z * wb.z; s01.w += ya.w * wb.w;
      s10.x += yb.x * wa.x; s10.y += yb.y * wa.y; s10.z += yb.z * wa.z; s10.w += yb.w * wa.w;
      s11.x += yb.x * wb.x; s11.y += yb.y * wb.y; s11.z += yb.z * wb.z; s11.w += yb.w * wb.w;
    }
    const float a00 = (s00.x + s00.y) + (s00.z + s00.w);
    const float a01 = (s01.x + s01.y) + (s01.z + s01.w);
    const float a10 = (s10.x + s10.y) + (s10.z + s10.w);
    const float a11 = (s11.x + s11.y) + (s11.z + s11.w);
#pragma unroll
    for (int rr = 0; rr < 2; ++rr) {
      const int ploc = pbase + rr - half * ROWS_;
      const int i = ploc >> 7, blow = ploc & 127;
      const int b_out = (mode == 0) ? half * 128 + blow : blow;
      const float v0 = (rr == 0) ? a00 : a10;
      const float v1 = (rr == 0) ? a01 : a11;
      dst[((size_t)(b_out * 8 + e0)) * 224 + i] = v0 + cadd0;
      dst[((size_t)(b_out * 8 + e1)) * 224 + i] = v1 + cadd1;
    }
  }
}

// ---------------------------------------------------------------------------
// Plain 64x64-tile bf16 MFMA GEMM (bf16 A input) — R3-verified version.
// mode 4: fout += acc + bias (out-proj residual); mode 5: fout = acc + bias.
// ---------------------------------------------------------------------------
__global__ __launch_bounds__(256) void gemm_plain(
    const u16* __restrict__ A, const u16* __restrict__ B,
    const float* __restrict__ bias, int mode, float* __restrict__ fout) {
  __shared__ u16 As[64 * 136];
  __shared__ u16 Bs[64 * 136];
  const int tid = threadIdx.x;
  const int M0 = blockIdx.x * 64, N0 = blockIdx.y * 64;
  const uint4* Ag = (const uint4*)(A + (size_t)M0 * 128);
  const uint4* Bg = (const uint4*)(B + (size_t)N0 * 128);
  for (int t = tid; t < 1024; t += 256) {
    int row = t >> 4, cc = t & 15;
    *(uint4*)&As[row * 136 + cc * 8] = Ag[row * 16 + cc];
  }
  for (int t = tid; t < 1024; t += 256) {
    int row = t >> 4, cc = t & 15;
    *(uint4*)&Bs[row * 136 + cc * 8] = Bg[row * 16 + cc];
  }
  __syncthreads();
  const int wave = tid >> 6, lane = tid & 63;
  const int wm = (wave >> 1) * 32, wn = (wave & 1) * 32;
  const int lr = lane & 15, kq = (lane >> 4) * 8;
  f32x4 acc[2][2] = {};
#pragma unroll
  for (int ks = 0; ks < 4; ++ks) {
    int ko = ks * 32 + kq;
    bf16x8 a0 = *(const bf16x8*)&As[(wm + lr) * 136 + ko];
    bf16x8 a1 = *(const bf16x8*)&As[(wm + 16 + lr) * 136 + ko];
    bf16x8 b0 = *(const bf16x8*)&Bs[(wn + lr) * 136 + ko];
    bf16x8 b1 = *(const bf16x8*)&Bs[(wn + 16 + lr) * 136 + ko];
    acc[0][0] = __builtin_amdgcn_mfma_f32_16x16x32_bf16(a0, b0, acc[0][0], 0, 0, 0);
    acc[0][1] = __builtin_amdgcn_mfma_f32_16x16x32_bf16(a0, b1, acc[0][1], 0, 0, 0);
    acc[1][0] = __builtin_amdgcn_mfma_f32_16x16x32_bf16(a1, b0, acc[1][0], 0, 0, 0);
    acc[1][1] = __builtin_amdgcn_mfma_f32_16x16x32_bf16(a1, b1, acc[1][1], 0, 0, 0);
  }
  const int colq = lane & 15, rowq = (lane >> 4) * 4;
#pragma unroll
  for (int tm = 0; tm < 2; ++tm)
#pragma unroll
    for (int tn = 0; tn < 2; ++tn) {
#pragma unroll
      for (int r = 0; r < 4; ++r) {
        int row = M0 + wm + tm * 16 + rowq + r;
        int col = N0 + wn + tn * 16 + colq;
        float v = acc[tm][tn][r] + bias[col];
        if (mode == 4) fout[(size_t)row * 128 + col] += v;
        else           fout[(size_t)row * 128 + col] = v;
      }
    }
}

// ---------------------------------------------------------------------------
// Self QKV GEMM: 128x128 tiles, 512 threads (8 waves, each 64x32). A from XB.
// ---------------------------------------------------------------------------
__global__ __launch_bounds__(512) void gemm_qkv_self(
    const u16* __restrict__ X, const u16* __restrict__ Bw,
    const float* __restrict__ bias, u16* __restrict__ o0, u16* __restrict__ o1,
    u16* __restrict__ o2) {
  __shared__ u16 As[128 * 136];
  __shared__ u16 Bs[128 * 136];
  const int tid = threadIdx.x;
  const int M0 = blockIdx.x * 128, N0 = blockIdx.y * 128;
  {
    const uint4* Bg = (const uint4*)(Bw + (size_t)N0 * 128);
    const uint4* Ag = (const uint4*)(X + (size_t)M0 * 128);
    for (int t = tid; t < 2048; t += 512) {
      int row = t >> 4, cc = t & 15;
      *(uint4*)&As[row * 136 + cc * 8] = Ag[row * 16 + cc];
      *(uint4*)&Bs[row * 136 + cc * 8] = Bg[row * 16 + cc];
    }
  }
  __syncthreads();
  const int wave = tid >> 6, lane = tid & 63;
  const int wm = (wave >> 2) * 64, wn = (wave & 3) * 32;
  const int lr = lane & 15, kq = (lane >> 4) * 8;
  f32x4 acc[4][2] = {};
#pragma unroll
  for (int ks = 0; ks < 4; ++ks) {
    int ko = ks * 32 + kq;
    bf16x8 b0 = *(const bf16x8*)&Bs[(wn + lr) * 136 + ko];
    bf16x8 b1 = *(const bf16x8*)&Bs[(wn + 16 + lr) * 136 + ko];
#pragma unroll
    for (int tm = 0; tm < 4; ++tm) {
      bf16x8 a0 = *(const bf16x8*)&As[(wm + tm * 16 + lr) * 136 + ko];
      acc[tm][0] = __builtin_amdgcn_mfma_f32_16x16x32_bf16(a0, b0, acc[tm][0], 0, 0, 0);
      acc[tm][1] = __builtin_amdgcn_mfma_f32_16x16x32_bf16(a0, b1, acc[tm][1], 0, 0, 0);
    }
  }
  const int colq = lane & 15, rowq = (lane >> 4) * 4;
#pragma unroll
  for (int tm = 0; tm < 4; ++tm)
#pragma unroll
    for (int tn = 0; tn < 2; ++tn) {
#pragma unroll
      for (int r = 0; r < 4; ++r) {
        int row = M0 + wm + tm * 16 + rowq + r;
        int col = N0 + wn + tn * 16 + colq;
        float v = acc[tm][tn][r] + bias[col];
        int part = col >> 7;
        int cc = col & 127;
        int e = cc >> 4, c = cc & 15;
        int rloc = row, badd = 0;
        if (row >= ROWS_) { rloc = row - ROWS_; badd = 128; }
        int b = (rloc & 127) + badd, pos = rloc >> 7;
        size_t off = ((size_t)(b * NH + e) * W_ + pos) * HD + c;
        if (part == 0)      o0[off] = f2bf(v * 0.25f);
        else if (part == 1) o1[off] = f2bf(v);
        else                o2[off] = f2bf(v);
      }
    }
}

// ---------------------------------------------------------------------------
// Cross QKV GEMM: 128x128 tiles, 512 threads.
// y=0: q from Xr (*0.25); y=1: K from Xl; y=2: V from Xl.
// At l=5 launched with grid.y=2 (V dead: no attn launch, corresp reads Q/K).
// ---------------------------------------------------------------------------
__global__ __launch_bounds__(512) void gemm_qkv_cross(
    const u16* __restrict__ Xl, const u16* __restrict__ Xr,
    const u16* __restrict__ cWi, const float* __restrict__ cbi,
    u16* __restrict__ QB, u16* __restrict__ KB, u16* __restrict__ VB) {
  __shared__ u16 As[128 * 136];
  __shared__ u16 Bs[128 * 136];
  const int tid = threadIdx.x;
  const int M0 = blockIdx.x * 128;
  const int y = blockIdx.y;
  const u16* X = (y == 0) ? Xr : Xl;
  const u16* Bw = cWi + (size_t)y * 128 * 128;
  const float* bias = cbi + y * 128;
  {
    const uint4* Bg = (const uint4*)Bw;
    const uint4* Ag = (const uint4*)(X + (size_t)M0 * 128);
    for (int t = tid; t < 2048; t += 512) {
      int row = t >> 4, cc = t & 15;
      *(uint4*)&As[row * 136 + cc * 8] = Ag[row * 16 + cc];
      *(uint4*)&Bs[row * 136 + cc * 8] = Bg[row * 16 + cc];
    }
  }
  __syncthreads();
  const int wave = tid >> 6, lane = tid & 63;
  const int wm = (wave >> 2) * 64, wn = (wave & 3) * 32;
  const int lr = lane & 15, kq = (lane >> 4) * 8;
  f32x4 acc[4][2] = {};
#pragma unroll
  for (int ks = 0; ks < 4; ++ks) {
    int ko = ks * 32 + kq;
    bf16x8 b0 = *(const bf16x8*)&Bs[(wn + lr) * 136 + ko];
    bf16x8 b1 = *(const bf16x8*)&Bs[(wn + 16 + lr) * 136 + ko];
#pragma unroll
    for (int tm = 0; tm < 4; ++tm) {
      bf16x8 a0 = *(const bf16x8*)&As[(wm + tm * 16 + lr) * 136 + ko];
      acc[tm][0] = __builtin_amdgcn_mfma_f32_16x16x32_bf16(a0, b0, acc[tm][0], 0, 0, 0);
      acc[tm][1] = __builtin_amdgcn_mfma_f32_16x16x32_bf16(a0, b1, acc[tm][1], 0, 0, 0);
    }
  }
  u16* outp = (y == 0) ? QB : ((y == 1) ? KB : VB);
  const float scale = (y == 0) ? 0.25f : 1.f;
  const int colq = lane & 15, rowq = (lane >> 4) * 4;
#pragma unroll
  for (int tm = 0; tm < 4; ++tm)
#pragma unroll
    for (int tn = 0; tn < 2; ++tn) {
#pragma unroll
      for (int r = 0; r < 4; ++r) {
        int row = M0 + wm + tm * 16 + rowq + r;
        int col = wn + tn * 16 + colq;
        float v = (acc[tm][tn][r] + bias[col]) * scale;
        int e = col >> 4, c = col & 15;
        int b = row & 127, pos = row >> 7;
        outp[((size_t)(b * NH + e) * W_ + pos) * HD + c] = f2bf(v);
      }
    }
}

// ---------------------------------------------------------------------------
// MFMA flash attention per (head e, batch-row b). Two-pass softmax. P stays
// in registers (sigma-permuted V); exp2 with log2e folded into Q-side staging.
// ---------------------------------------------------------------------------
__global__ __launch_bounds__(448) void attn_kernel(
    const u16* __restrict__ qb, const u16* __restrict__ kb,
    const u16* __restrict__ vb, const float* __restrict__ ALPHA,
    const float* __restrict__ BETA, const float* __restrict__ GAMMA,
    const float* __restrict__ DELTA, u16* __restrict__ obuf) {
  __shared__ u16 Ksh[224 * KSTR];
  __shared__ u16 Qsh[224 * KSTR];
  __shared__ u16 Vt[16 * VSTR];
  const int e = blockIdx.x, b = blockIdx.y;
  const size_t hb = (size_t)(b * NH + e);
  const int tid = threadIdx.x;
  const u32 ONE = 0x3F80u;
  const float LOG2E = 1.4426950408889634f;

  if (tid < 224) {
    const int j = tid;
    const uint4* src = (const uint4*)(kb + (hb * W_ + j) * HD);
    uint4 a = src[0], b2 = src[1];
    *(uint4*)&Ksh[j * KSTR] = a;
    *(uint4*)&Ksh[j * KSTR + 8] = b2;
    float G = GAMMA[hb * 224 + j];
    float D = DELTA[hb * 224 + j];
    float jf = (float)j;
    float P = (G * jf + D) * LOG2E;
    u16 Phi = f2bf(P);
    float Plo = P - __uint_as_float((u32)Phi << 16);
    u32* ex = (u32*)&Ksh[j * KSTR + 16];
    ex[0] = (u32)f2bf(G * LOG2E) | ((u32)Phi << 16);
    ex[1] = (u32)f2bf(Plo) | ((u32)f2bf(jf) << 16);
    ex[2] = ONE | (ONE << 16);
#pragma unroll
    for (int z = 3; z < 12; ++z) ex[z] = 0;
    const uint4* vsrc = (const uint4*)(vb + (hb * W_ + j) * HD);
    uint4 va = vsrc[0], vb4 = vsrc[1];
    u32 w[8] = {va.x, va.y, va.z, va.w, vb4.x, vb4.y, vb4.z, vb4.w};
    // sigma-permuted column so PV A-fragments come straight from registers
    const int jl = j & 31;
    const int qcol = (j & ~31) | (((jl >> 2) & 3) << 3) | ((jl >> 4) << 2) | (jl & 3);
#pragma unroll
    for (int c = 0; c < 16; ++c)
      Vt[c * VSTR + qcol] = (c & 1) ? (u16)(w[c >> 1] >> 16) : (u16)(w[c >> 1] & 0xFFFF);
  } else {
    const int i = tid - 224;
    const uint4* src = (const uint4*)(qb + (hb * W_ + i) * HD);
    uint4 a = src[0], b2 = src[1];
    u32 qa[8] = {a.x, a.y, a.z, a.w, b2.x, b2.y, b2.z, b2.w};
#pragma unroll
    for (int t = 0; t < 8; ++t)
      qa[t] = cvtpk(bflo(qa[t]) * LOG2E, bfhi(qa[t]) * LOG2E);
    *(uint4*)&Qsh[i * KSTR] = make_uint4(qa[0], qa[1], qa[2], qa[3]);
    *(uint4*)&Qsh[i * KSTR + 8] = make_uint4(qa[4], qa[5], qa[6], qa[7]);
    float al = ALPHA[hb * 224 + i];
    float be = BETA[hb * 224 + i];
    float ifl = (float)i;
    float Q = (be - al * ifl) * LOG2E;
    u16 Qhi = f2bf(Q);
    float Qlo = Q - __uint_as_float((u32)Qhi << 16);
    u32* ex = (u32*)&Qsh[i * KSTR + 16];
    ex[0] = (u32)f2bf(-ifl) | (ONE << 16);
    ex[1] = ONE | ((u32)f2bf(al * LOG2E) << 16);
    ex[2] = (u32)Qhi | ((u32)f2bf(Qlo) << 16);
#pragma unroll
    for (int z = 3; z < 12; ++z) ex[z] = 0;
  }
  __syncthreads();

  const int wid = tid >> 6, lane = tid & 63;
  const int g = lane >> 4, li = lane & 15;
  const int obase = (b & 128) ? ROWS_ : 0;
  const int blow = b & 127;

  for (int qt = wid * 2; qt < wid * 2 + 2; ++qt) {
    const int i0 = qt * 16;
    const bf16x8 Bq = *(const bf16x8*)&Qsh[(i0 + li) * KSTR + g * 8];
    f32x4 C[7][2];
#pragma unroll
    for (int js = 0; js < 7; ++js) {
      const bf16x8 A0 = *(const bf16x8*)&Ksh[(js * 32 + li) * KSTR + g * 8];
      const bf16x8 A1 = *(const bf16x8*)&Ksh[(js * 32 + 16 + li) * KSTR + g * 8];
      const f32x4 Z = {0.f, 0.f, 0.f, 0.f};
      C[js][0] = __builtin_amdgcn_mfma_f32_16x16x32_bf16(A0, Bq, Z, 0, 0, 0);
      C[js][1] = __builtin_amdgcn_mfma_f32_16x16x32_bf16(A1, Bq, Z, 0, 0, 0);
    }
    float m = -1e30f;
#pragma unroll
    for (int js = 0; js < 7; ++js)
#pragma unroll
      for (int h = 0; h < 2; ++h)
        m = fmaxf(m, fmaxf(fmaxf(C[js][h][0], C[js][h][1]), fmaxf(C[js][h][2], C[js][h][3])));
    m = fmaxf(m, __shfl_xor(m, 16));
    m = fmaxf(m, __shfl_xor(m, 32));
    f32x4 O = {0.f, 0.f, 0.f, 0.f};
    float lsum = 0.f;
#pragma unroll
    for (int js = 0; js < 7; ++js) {
      float p0 = EX2(C[js][0][0] - m), p1 = EX2(C[js][0][1] - m);
      float p2 = EX2(C[js][0][2] - m), p3 = EX2(C[js][0][3] - m);
      float p4 = EX2(C[js][1][0] - m), p5 = EX2(C[js][1][1] - m);
      float p6 = EX2(C[js][1][2] - m), p7 = EX2(C[js][1][3] - m);
      lsum += ((p0 + p1) + (p2 + p3)) + ((p4 + p5) + (p6 + p7));
      uint4 pu = make_uint4(cvtpk(p0, p1), cvtpk(p2, p3), cvtpk(p4, p5), cvtpk(p6, p7));
      const bf16x8 Ap = __builtin_bit_cast(bf16x8, pu);
      const bf16x8 Bv = *(const bf16x8*)&Vt[li * VSTR + js * 32 + g * 8];
      O = __builtin_amdgcn_mfma_f32_16x16x32_bf16(Ap, Bv, O, 0, 0, 0);
    }
    lsum += __shfl_xor(lsum, 16);
    lsum += __shfl_xor(lsum, 32);
#pragma unroll
    for (int r = 0; r < 4; ++r) {
      const float lr = __shfl(lsum, g * 4 + r);
      const int irow = i0 + g * 4 + r;
      obuf[((size_t)(obase + irow * 128 + blow)) * C_ + e * HD + li] = f2bf(O[r] * (1.f / lr));
    }
  }
}

// Gather x_l/x_r[b][c][h][w] -> bf16 rows p = img*28672 + w*128 + h*2 + b.
__global__ __launch_bounds__(256) void transpose_kernel(const float* __restrict__ x_l,
                                                        const float* __restrict__ x_r,
                                                        u16* __restrict__ xT) {
  __shared__ float tile[128][57];
  const int wt = blockIdx.x * 56, hi = blockIdx.y;
  const int img = blockIdx.z >> 1, bi = blockIdx.z & 1;
  const float* x = img ? x_r : x_l;
  const int wave = threadIdx.x >> 6, lane = threadIdx.x & 63;
  for (int c = wave; c < 128; c += 4) {
    if (lane < 56)
      tile[c][lane] = x[(((size_t)bi * 128 + c) * 64 + hi) * 224 + wt + lane];
  }
  __syncthreads();
  u32* dst = (u32*)xT;
  for (int w = wave; w < 56; w += 4) {
    int p = img * ROWS_ + (wt + w) * 128 + hi * 2 + bi;
    float a = tile[lane * 2][w], b2 = tile[lane * 2 + 1][w];
    dst[(size_t)p * 64 + lane] = (u32)f2bf(a) | ((u32)f2bf(b2) << 16);
  }
}

// ---------------------------------------------------------------------------
// Final soft-argmax, MFMA version.
// ---------------------------------------------------------------------------
__global__ __launch_bounds__(448) void corresp_kernel(
    const u16* __restrict__ qb, const u16* __restrict__ kb,
    const float* __restrict__ ALPHA, const float* __restrict__ BETA,
    const float* __restrict__ GAMMA, const float* __restrict__ DELTA,
    float* __restrict__ out) {
  __shared__ u16 Ksh[224 * 136];   // 60,928 B
  __shared__ float Gs[224], Ds[224];
  const int b = blockIdx.x, tid = threadIdx.x;
  if (tid < 224) {
    const int j = tid;
#pragma unroll
    for (int e = 0; e < 8; ++e) {
      const uint4* src = (const uint4*)(kb + ((size_t)(b * 8 + e) * 224 + j) * 16);
      *(uint4*)&Ksh[j * 136 + e * 16] = src[0];
      *(uint4*)&Ksh[j * 136 + e * 16 + 8] = src[1];
    }
    float gs = 0.f, ds = 0.f;
#pragma unroll
    for (int e = 0; e < 8; ++e) {
      gs += GAMMA[((size_t)(b * 8 + e)) * 224 + j];
      ds += DELTA[((size_t)(b * 8 + e)) * 224 + j];
    }
    Gs[j] = gs;
    Ds[j] = ds;
  }
  __syncthreads();
  const int wid = tid >> 6, lane = tid & 63;
  const int g = lane >> 4, li = lane & 15;
  const int i = blockIdx.y * 112 + wid * 16 + li;
  bf16x8 Bq[4];
#pragma unroll
  for (int ks = 0; ks < 4; ++ks) {
    const int e2 = ks * 2 + (g >> 1), c0 = (g & 1) * 8;
    Bq[ks] = *(const bf16x8*)&qb[((size_t)(b * 8 + e2) * 224 + i) * 16 + c0];
  }
  f32x4 C[14];
#pragma unroll
  for (int js = 0; js < 14; ++js) {
    f32x4 acc = {0.f, 0.f, 0.f, 0.f};
#pragma unroll
    for (int ks = 0; ks < 4; ++ks) {
      const bf16x8 A = *(const bf16x8*)&Ksh[(js * 16 + li) * 136 + ks * 32 + g * 8];
      acc = __builtin_amdgcn_mfma_f32_16x16x32_bf16(A, Bq[ks], acc, 0, 0, 0);
    }
    C[js] = acc;
  }
  float ai = 0.f, bi_ = 0.f;
#pragma unroll
  for (int e = 0; e < 8; ++e) {
    ai += ALPHA[((size_t)(b * 8 + e)) * 224 + i];
    bi_ += BETA[((size_t)(b * 8 + e)) * 224 + i];
  }
  const float ifl = (float)i;
  float m = -1e30f;
#pragma unroll
  for (int js = 0; js < 14; ++js) {
#pragma unroll
    for (int r = 0; r < 4; ++r) {
      const int j = js * 16 + g * 4 + r;
      float s = C[js][r] + ((float)j - ifl) * (ai + Gs[j]) + bi_ + Ds[j];
      C[js][r] = s;
      m = fmaxf(m, s);
    }
  }
  m = fmaxf(m, __shfl_xor(m, 16));
  m = fmaxf(m, __shfl_xor(m, 32));
  float l = 0.f, wj = 0.f;
#pragma unroll
  for (int js = 0; js < 14; ++js) {
#pragma unroll
    for (int r = 0; r < 4; ++r) {
      const float p = __expf(C[js][r] - m);
      l += p;
      wj += p * (float)(js * 16 + g * 4 + r);
    }
  }
  l += __shfl_xor(l, 16);
  l += __shfl_xor(l, 32);
  wj += __shfl_xor(wj, 16);
  wj += __shfl_xor(wj, 32);
  if (g == 0) out[(size_t)b * 224 + i] = ifl - wj / fmaxf(l, 1e-30f);
}

// Single-launch conversion of all five weight tensors to one bf16 buffer.
#define OFF_FEAT 0
#define OFF_SWI 16384
#define OFF_SWO 311296
#define OFF_CWI 409600
#define OFF_CWO 704512
#define N_WALL 802816
__global__ __launch_bounds__(256) void cvt_all_kernel(
    const float* __restrict__ feat_w, const float* __restrict__ self_Wi,
    const float* __restrict__ self_Wo, const float* __restrict__ cross_Wi,
    const float* __restrict__ cross_Wo, u16* __restrict__ dst) {
  int idx = blockIdx.x * 256 + threadIdx.x;
  if (idx >= N_WALL) return;
  float v;
  if (idx < OFF_SWI)       v = feat_w[idx];
  else if (idx < OFF_SWO)  v = self_Wi[idx - OFF_SWI];
  else if (idx < OFF_CWI)  v = self_Wo[idx - OFF_SWO];
  else if (idx < OFF_CWO)  v = cross_Wi[idx - OFF_CWI];
  else                     v = cross_Wo[idx - OFF_CWO];
  dst[idx] = f2bf(v);
}

extern "C" void kernel_launch(void* const* d_in, const int* in_sizes, int n_in,
                              void* d_out, int out_size, void* d_ws, size_t ws_size,
                              hipStream_t stream) {
  (void)in_sizes; (void)n_in; (void)out_size; (void)ws_size;
  const float* x_l = (const float*)d_in[0];
  const float* x_r = (const float*)d_in[1];
  const float* feat_w = (const float*)d_in[2];
  const float* feat_b = (const float*)d_in[3];
  const float* self_Wi = (const float*)d_in[4];
  const float* self_bi = (const float*)d_in[5];
  const float* self_Wo = (const float*)d_in[6];
  const float* self_bo = (const float*)d_in[7];
  const float* cross_Wi = (const float*)d_in[8];
  const float* cross_bi = (const float*)d_in[9];
  const float* cross_Wo = (const float*)d_in[10];
  const float* cross_bo = (const float*)d_in[11];
  const float* ln_g = (const float*)d_in[12];
  const float* ln_b = (const float*)d_in[13];

  char* ws = (char*)d_ws;
  size_t off = 0;
  auto alloc = [&](size_t bytes) {
    char* p = ws + off;
    off += (bytes + 255) & ~(size_t)255;
    return p;
  };
  // Total ~97 MB — under the R6-proven ~112 MB budget. XB aliases OB:
  // XB live range is tab->qkv, OB live range is attn->out-proj (disjoint).
  float* XA = (float*)alloc((size_t)2 * ROWS_ * C_ * 4);   // residual (in-place LN)
  u16* QB = (u16*)alloc((size_t)256 * NH * W_ * HD * 2);   // also XT scratch
  u16* KB = (u16*)alloc((size_t)256 * NH * W_ * HD * 2);
  u16* VB = (u16*)alloc((size_t)256 * NH * W_ * HD * 2);
  u16* OB = (u16*)alloc((size_t)2 * ROWS_ * C_ * 2);
  u16* WALL = (u16*)alloc((size_t)N_WALL * 2);
  float* PREP = (float*)alloc((size_t)12 * PREP_STRIDE * 4);
  float* ALPHA = (float*)alloc((size_t)256 * NH * W_ * 4);
  float* BETA = (float*)alloc((size_t)256 * NH * W_ * 4);
  float* GAMMA = (float*)alloc((size_t)256 * NH * W_ * 4);
  float* DELTA = (float*)alloc((size_t)256 * NH * W_ * 4);
  u16* XB = OB;   // alias — disjoint live ranges

  cvt_all_kernel<<<3136, 256, 0, stream>>>(feat_w, self_Wi, self_Wo, cross_Wi, cross_Wo, WALL);
  prep_kernel<<<dim3(12, 8), 256, 0, stream>>>(self_Wi, self_bi, cross_Wi, cross_bi, PREP);

  transpose_kernel<<<dim3(4, 64, 4), 256, 0, stream>>>(x_l, x_r, QB);
  gemm_plain<<<dim3(896, 2), 256, 0, stream>>>(QB, WALL + OFF_FEAT, feat_b, 5, XA);

  for (int l = 0; l < 6; ++l) {
    const u16* sWi = WALL + OFF_SWI + (size_t)l * 384 * 128;
    const u16* sWo = WALL + OFF_SWO + (size_t)l * 128 * 128;
    const u16* cWi = WALL + OFF_CWI + (size_t)l * 384 * 128;
    const u16* cWo = WALL + OFF_CWO + (size_t)l * 128 * 128;
    const float* sbi = self_bi + l * 384;
    const float* sbo = self_bo + l * 128;
    const float* cbi = cross_bi + l * 384;
    const float* cbo = cross_bo + l * 128;
    const float* ps = PREP + (size_t)(l * 2) * PREP_STRIDE;
    const float* pc = PREP + (size_t)(l * 2 + 1) * PREP_STRIDE;

    // --- self attention on xl AND xr: X = LN(X) (+tables+XB), qkv, attn, +=proj ---
    tab_kernel<<<1792, 256, 0, stream>>>(XA, ln_g, ln_b, ps, ps + 4096, ALPHA, BETA,
                                         ps + 2048, ps + 4112, GAMMA, DELTA, XB, 0);
    gemm_qkv_self<<<dim3(448, 3), 512, 0, stream>>>(XB, sWi, sbi, QB, KB, VB);
    attn_kernel<<<dim3(8, 256), 448, 0, stream>>>(QB, KB, VB, ALPHA, BETA, GAMMA, DELTA, OB);
    gemm_plain<<<dim3(896, 2), 256, 0, stream>>>(OB, sWo, sbo, 4, XA);

    // --- cross attention: q from xr, k/v from xl; X = LN(X) first ---
    tab_kernel<<<1792, 256, 0, stream>>>(XA, ln_g, ln_b, pc, pc + 4096, ALPHA, BETA,
                                         pc + 2048, pc + 4112, GAMMA, DELTA, XB, 1);
    // l==5: V (y=2) is dead — no attn launch follows and corresp reads QB/KB only.
    gemm_qkv_cross<<<dim3(224, (l < 5) ? 3 : 2), 512, 0, stream>>>(
        XB, XB + (size_t)ROWS_ * C_, cWi, cbi, QB, KB, VB);
    if (l < 5) {
      attn_kernel<<<dim3(8, 128), 448, 0, stream>>>(QB, KB, VB, ALPHA, BETA, GAMMA, DELTA, OB);
      gemm_plain<<<dim3(448, 2), 256, 0, stream>>>(OB, cWo, cbo, 4, XA);  // xl half only
    }
    // l == 5: attention output / x updates dead; corresp reads QB/KB + tables.
  }
  corresp_kernel<<<dim3(128, 2), 448, 0, stream>>>(QB, KB, ALPHA, BETA, GAMMA, DELTA,
                                                   (float*)d_out);
}

// Round 13
// 1150.432 us; speedup vs baseline: 1.0107x; 1.0003x over previous
//
#include <hip/hip_runtime.h>

typedef unsigned short u16;
typedef unsigned int u32;

#define W_ 224
#define H_ 128
#define C_ 128
#define NH 8
#define HD 16
#define ROWS_ (W_ * H_)          // 28672 rows per image
#define PREP_STRIDE 4128
#define KSTR 40
#define VSTR 232
#define TROWS 32                 // rows per tab_kernel block

typedef __bf16 bf16x8 __attribute__((ext_vector_type(8)));
typedef float f32x4 __attribute__((ext_vector_type(4)));

__device__ __forceinline__ u16 f2bf(float f) {
  u32 u = __float_as_uint(f);
  return (u16)((u + 0x7FFFu + ((u >> 16) & 1u)) >> 16);
}
// Packed RNE f32->bf16 pair: single v_cvt_pk_bf16_f32 (same rounding as f2bf).
__device__ __forceinline__ u32 cvtpk(float lo, float hi) {
  u32 r;
  asm("v_cvt_pk_bf16_f32 %0, %1, %2" : "=v"(r) : "v"(lo), "v"(hi));
  return r;
}
__device__ __forceinline__ float bflo(u32 u) { return __uint_as_float(u << 16); }
__device__ __forceinline__ float bfhi(u32 u) { return __uint_as_float(u & 0xFFFF0000u); }

#if __has_builtin(__builtin_amdgcn_exp2f)
#define EX2(x) __builtin_amdgcn_exp2f(x)
#else
#define EX2(x) __expf((x) * 0.6931471805599453f)
#endif

// ---------------------------------------------------------------------------
// Rank-1 PE decomposition prep: grid (12 s, 8 e-groups), LDS-staged, coalesced.
// ---------------------------------------------------------------------------
__global__ __launch_bounds__(256) void prep_kernel(
    const float* __restrict__ self_Wi, const float* __restrict__ self_bi,
    const float* __restrict__ cross_Wi, const float* __restrict__ cross_bi,
    float* __restrict__ prep) {
  __shared__ float Wq[16][132];
  __shared__ float Wk[16][132];
  __shared__ float u[128];
  __shared__ float Aq[16], Ak[16], bq[16], bk[16];
  const int s = blockIdx.x, e = blockIdx.y, l = s >> 1;
  const float* Wi = (s & 1) ? cross_Wi + (size_t)l * 384 * 128 : self_Wi + (size_t)l * 384 * 128;
  const float* bi = (s & 1) ? cross_bi + l * 384 : self_bi + l * 384;
  const int tid = threadIdx.x;
  if (tid < 128) {
    float ex = (float)(tid & ~1) * (1.f / 128.f);
    u[tid] = expf(-ex * logf(10000.f));
  }
  if (tid >= 128 && tid < 144) { int r = tid - 128; bq[r] = bi[e * 16 + r]; }
  if (tid >= 160 && tid < 176) { int r = tid - 160; bk[r] = bi[128 + e * 16 + r]; }
  for (int t = tid; t < 2048; t += 256) {
    int r = t >> 7, f = t & 127;
    Wq[r][f] = Wi[(size_t)(e * 16 + r) * 128 + f];
    Wk[r][f] = Wi[(size_t)(128 + e * 16 + r) * 128 + f];
  }
  __syncthreads();
  {
    const int grp = tid >> 3;
    const int lg = tid & 7;
    const float* row = (grp < 16) ? Wq[grp] : Wk[grp - 16];
    float a = 0.f;
#pragma unroll
    for (int i = 0; i < 16; ++i) a += row[lg * 16 + i] * u[lg * 16 + i];
    a += __shfl_xor(a, 1);
    a += __shfl_xor(a, 2);
    a += __shfl_xor(a, 4);
    if (lg == 0) {
      if (grp < 16) Aq[grp] = a;
      else          Ak[grp - 16] = a;
    }
  }
  __syncthreads();
  float* out = prep + (size_t)s * PREP_STRIDE;
  for (int t = tid; t < 512; t += 256) {
    int v = t >> 7, f = t & 127;
    float acc = 0.f;
#pragma unroll
    for (int c = 0; c < 16; ++c) {
      if (v == 0)      acc += Wq[c][f] * Ak[c];
      else if (v == 1) acc += Wq[c][f] * bk[c];
      else if (v == 2) acc += Wk[c][f] * Aq[c];
      else             acc += Wk[c][f] * bq[c];
    }
    out[v * 1024 + e * 128 + f] = acc * 0.25f;
  }
  if (tid < 4) {
    int v = tid;
    float acc = 0.f;
#pragma unroll
    for (int c = 0; c < 16; ++c) {
      if (v == 0)      acc += bq[c] * Ak[c];
      else if (v == 1) acc += bq[c] * bk[c];
      else if (v == 2) acc += bk[c] * Aq[c];
      else             acc += bk[c] * bq[c];
    }
    out[4096 + v * 8 + e] = acc * 0.25f;
  }
}

// ---------------------------------------------------------------------------
// Fused LN + affine-PE tables, 32 rows per block (R10-verified). Phase-2:
// 2x2 map; 128 b128 reads per 4 outputs; tables bit-identical.
// ---------------------------------------------------------------------------
__global__ __launch_bounds__(256) void tab_kernel(
    float* __restrict__ x, const float* __restrict__ g,
    const float* __restrict__ b, const float* __restrict__ wq,
    const float* __restrict__ cq, float* __restrict__ outA, float* __restrict__ outB,
    const float* __restrict__ wk, const float* __restrict__ ck,
    float* __restrict__ outG, float* __restrict__ outD,
    u16* __restrict__ xb, int mode) {
  __shared__ float ys[TROWS][132];
  __shared__ float ws[32][132];
  const int tid = threadIdx.x;
  for (int t = tid; t < 2048; t += 256) ws[t >> 7][t & 127] = wq[t];
  for (int t = tid; t < 2048; t += 256) ws[16 + (t >> 7)][t & 127] = wk[t];
  const int wv = tid >> 6, lane = tid & 63;
  const int base = blockIdx.x * TROWS;
  {
    float2 gg = ((const float2*)g)[lane];
    float2 bb = ((const float2*)b)[lane];
    // batch the 8 row loads (independent, in flight together)
    float2 vv[8];
#pragma unroll
    for (int t = 0; t < 8; ++t) {
      const int r = wv * 8 + t;
      vv[t] = ((const float2*)(x + (size_t)(base + r) * 128))[lane];
    }
    // 8 independent reduce+write chains; compiler interleaves across VALU
#pragma unroll
    for (int t = 0; t < 8; ++t) {
      const int r = wv * 8 + t;
      float2 v = vv[t];
      float s1 = v.x + v.y, s2 = v.x * v.x + v.y * v.y;
#pragma unroll
      for (int k = 1; k < 64; k <<= 1) {
        s1 += __shfl_xor(s1, k);
        s2 += __shfl_xor(s2, k);
      }
      float mean = s1 * (1.f / 128.f);
      float var = s2 * (1.f / 128.f) - mean * mean;
      float rstd = rsqrtf(var + 1e-5f);
      float y0 = (v.x - mean) * rstd * gg.x + bb.x;
      float y1 = (v.y - mean) * rstd * gg.y + bb.y;
      ((float2*)(x + (size_t)(base + r) * 128))[lane] = make_float2(y0, y1);
      ((u32*)xb)[(size_t)(base + r) * 64 + lane] = cvtpk(y0, y1);
      ys[r][2 * lane] = y0;
      ys[r][2 * lane + 1] = y1;
    }
  }
  __syncthreads();
  // 2x2 remap: thread (c2 = tid&15, rg2 = tid>>4) owns cols {2c2,2c2+1},
  // rows {2rg2, 2rg2+1}. 16x16 threads cover 32x32 outputs.
  const int c2 = tid & 15;
  const int rg2 = tid >> 4;
  const int c0 = c2 * 2;
  const int row0 = rg2 * 2;
  const int side = c0 >> 4;              // same for both cols (even start)
  const int val = (c0 & 15) >> 3;        // same for both cols
  const int e0 = c0 & 7, e1 = (c0 + 1) & 7;
  const float cadd0 = side ? ck[val * 8 + e0] : cq[val * 8 + e0];
  const float cadd1 = side ? ck[val * 8 + e1] : cq[val * 8 + e1];
  float* dst = side ? (val ? outD : outG) : (val ? outB : outA);
  // rows never straddle ROWS_ (28672 = 896*32): half uniform per block
  const int pbase = base + row0;
  const int half = (pbase >= ROWS_) ? 1 : 0;
  const bool active = (mode == 0) || (half ? (side == 0) : (side == 1));
  if (active) {
    const float4* w0 = (const float4*)&ws[c0][0];
    const float4* w1 = (const float4*)&ws[c0 + 1][0];
    const float4* y0 = (const float4*)&ys[row0][0];
    const float4* y1 = (const float4*)&ys[row0 + 1][0];
    float4 s00 = {0.f, 0.f, 0.f, 0.f}, s01 = s00, s10 = s00, s11 = s00;
#pragma unroll 4
    for (int f4 = 0; f4 < 32; ++f4) {
      float4 wa = w0[f4], wb = w1[f4];
      float4 ya = y0[f4], yb = y1[f4];
      s00.x += ya.x * wa.x; s00.y += ya.y * wa.y; s00.z += ya.z * wa.z; s00.w += ya.w * wa.w;
      s01.x += ya.x * wb.x; s01.y += ya.y * wb.y; s01.z += ya.z * wb.z; s01.w += ya.w * wb.w;
      s10.x += yb.x * wa.x; s10.y += yb.y * wa.y; s10.z += yb.z * wa.z; s10.w += yb.w * wa.w;
      s11.x += yb.x * wb.x; s11.y += yb.y * wb.y; s11.z += yb.z * wb.z; s11.w += yb.w * wb.w;
    }
    const float a00 = (s00.x + s00.y) + (s00.z + s00.w);
    const float a01 = (s01.x + s01.y) + (s01.z + s01.w);
    const float a10 = (s10.x + s10.y) + (s10.z + s10.w);
    const float a11 = (s11.x + s11.y) + (s11.z + s11.w);
#pragma unroll
    for (int rr = 0; rr < 2; ++rr) {
      const int ploc = pbase + rr - half * ROWS_;
      const int i = ploc >> 7, blow = ploc & 127;
      const int b_out = (mode == 0) ? half * 128 + blow : blow;
      const float v0 = (rr == 0) ? a00 : a10;
      const float v1 = (rr == 0) ? a01 : a11;
      dst[((size_t)(b_out * 8 + e0)) * 224 + i] = v0 + cadd0;
      dst[((size_t)(b_out * 8 + e1)) * 224 + i] = v1 + cadd1;
    }
  }
}

// ---------------------------------------------------------------------------
// Plain 64x64-tile bf16 MFMA GEMM (bf16 A input) — R3-verified version.
// mode 4: fout += acc + bias (out-proj residual); mode 5: fout = acc + bias.
// ---------------------------------------------------------------------------
__global__ __launch_bounds__(256) void gemm_plain(
    const u16* __restrict__ A, const u16* __restrict__ B,
    const float* __restrict__ bias, int mode, float* __restrict__ fout) {
  __shared__ u16 As[64 * 136];
  __shared__ u16 Bs[64 * 136];
  const int tid = threadIdx.x;
  const int M0 = blockIdx.x * 64, N0 = blockIdx.y * 64;
  const uint4* Ag = (const uint4*)(A + (size_t)M0 * 128);
  const uint4* Bg = (const uint4*)(B + (size_t)N0 * 128);
  for (int t = tid; t < 1024; t += 256) {
    int row = t >> 4, cc = t & 15;
    *(uint4*)&As[row * 136 + cc * 8] = Ag[row * 16 + cc];
  }
  for (int t = tid; t < 1024; t += 256) {
    int row = t >> 4, cc = t & 15;
    *(uint4*)&Bs[row * 136 + cc * 8] = Bg[row * 16 + cc];
  }
  __syncthreads();
  const int wave = tid >> 6, lane = tid & 63;
  const int wm = (wave >> 1) * 32, wn = (wave & 1) * 32;
  const int lr = lane & 15, kq = (lane >> 4) * 8;
  f32x4 acc[2][2] = {};
#pragma unroll
  for (int ks = 0; ks < 4; ++ks) {
    int ko = ks * 32 + kq;
    bf16x8 a0 = *(const bf16x8*)&As[(wm + lr) * 136 + ko];
    bf16x8 a1 = *(const bf16x8*)&As[(wm + 16 + lr) * 136 + ko];
    bf16x8 b0 = *(const bf16x8*)&Bs[(wn + lr) * 136 + ko];
    bf16x8 b1 = *(const bf16x8*)&Bs[(wn + 16 + lr) * 136 + ko];
    acc[0][0] = __builtin_amdgcn_mfma_f32_16x16x32_bf16(a0, b0, acc[0][0], 0, 0, 0);
    acc[0][1] = __builtin_amdgcn_mfma_f32_16x16x32_bf16(a0, b1, acc[0][1], 0, 0, 0);
    acc[1][0] = __builtin_amdgcn_mfma_f32_16x16x32_bf16(a1, b0, acc[1][0], 0, 0, 0);
    acc[1][1] = __builtin_amdgcn_mfma_f32_16x16x32_bf16(a1, b1, acc[1][1], 0, 0, 0);
  }
  const int colq = lane & 15, rowq = (lane >> 4) * 4;
#pragma unroll
  for (int tm = 0; tm < 2; ++tm)
#pragma unroll
    for (int tn = 0; tn < 2; ++tn) {
#pragma unroll
      for (int r = 0; r < 4; ++r) {
        int row = M0 + wm + tm * 16 + rowq + r;
        int col = N0 + wn + tn * 16 + colq;
        float v = acc[tm][tn][r] + bias[col];
        if (mode == 4) fout[(size_t)row * 128 + col] += v;
        else           fout[(size_t)row * 128 + col] = v;
      }
    }
}

// ---------------------------------------------------------------------------
// Self QKV GEMM: 128x128 tiles, 512 threads (8 waves, each 64x32). A from XB.
// ---------------------------------------------------------------------------
__global__ __launch_bounds__(512) void gemm_qkv_self(
    const u16* __restrict__ X, const u16* __restrict__ Bw,
    const float* __restrict__ bias, u16* __restrict__ o0, u16* __restrict__ o1,
    u16* __restrict__ o2) {
  __shared__ u16 As[128 * 136];
  __shared__ u16 Bs[128 * 136];
  const int tid = threadIdx.x;
  const int M0 = blockIdx.x * 128, N0 = blockIdx.y * 128;
  {
    const uint4* Bg = (const uint4*)(Bw + (size_t)N0 * 128);
    const uint4* Ag = (const uint4*)(X + (size_t)M0 * 128);
    for (int t = tid; t < 2048; t += 512) {
      int row = t >> 4, cc = t & 15;
      *(uint4*)&As[row * 136 + cc * 8] = Ag[row * 16 + cc];
      *(uint4*)&Bs[row * 136 + cc * 8] = Bg[row * 16 + cc];
    }
  }
  __syncthreads();
  const int wave = tid >> 6, lane = tid & 63;
  const int wm = (wave >> 2) * 64, wn = (wave & 3) * 32;
  const int lr = lane & 15, kq = (lane >> 4) * 8;
  f32x4 acc[4][2] = {};
#pragma unroll
  for (int ks = 0; ks < 4; ++ks) {
    int ko = ks * 32 + kq;
    bf16x8 b0 = *(const bf16x8*)&Bs[(wn + lr) * 136 + ko];
    bf16x8 b1 = *(const bf16x8*)&Bs[(wn + 16 + lr) * 136 + ko];
#pragma unroll
    for (int tm = 0; tm < 4; ++tm) {
      bf16x8 a0 = *(const bf16x8*)&As[(wm + tm * 16 + lr) * 136 + ko];
      acc[tm][0] = __builtin_amdgcn_mfma_f32_16x16x32_bf16(a0, b0, acc[tm][0], 0, 0, 0);
      acc[tm][1] = __builtin_amdgcn_mfma_f32_16x16x32_bf16(a0, b1, acc[tm][1], 0, 0, 0);
    }
  }
  const int colq = lane & 15, rowq = (lane >> 4) * 4;
#pragma unroll
  for (int tm = 0; tm < 4; ++tm)
#pragma unroll
    for (int tn = 0; tn < 2; ++tn) {
#pragma unroll
      for (int r = 0; r < 4; ++r) {
        int row = M0 + wm + tm * 16 + rowq + r;
        int col = N0 + wn + tn * 16 + colq;
        float v = acc[tm][tn][r] + bias[col];
        int part = col >> 7;
        int cc = col & 127;
        int e = cc >> 4, c = cc & 15;
        int rloc = row, badd = 0;
        if (row >= ROWS_) { rloc = row - ROWS_; badd = 128; }
        int b = (rloc & 127) + badd, pos = rloc >> 7;
        size_t off = ((size_t)(b * NH + e) * W_ + pos) * HD + c;
        if (part == 0)      o0[off] = f2bf(v * 0.25f);
        else if (part == 1) o1[off] = f2bf(v);
        else                o2[off] = f2bf(v);
      }
    }
}

// ---------------------------------------------------------------------------
// Cross QKV GEMM: 128x128 tiles, 512 threads.
// y=0: q from Xr (*0.25); y=1: K from Xl; y=2: V from Xl.
// At l=5 launched with grid.y=2 (V dead: no attn launch, corresp reads Q/K).
// ---------------------------------------------------------------------------
__global__ __launch_bounds__(512) void gemm_qkv_cross(
    const u16* __restrict__ Xl, const u16* __restrict__ Xr,
    const u16* __restrict__ cWi, const float* __restrict__ cbi,
    u16* __restrict__ QB, u16* __restrict__ KB, u16* __restrict__ VB) {
  __shared__ u16 As[128 * 136];
  __shared__ u16 Bs[128 * 136];
  const int tid = threadIdx.x;
  const int M0 = blockIdx.x * 128;
  const int y = blockIdx.y;
  const u16* X = (y == 0) ? Xr : Xl;
  const u16* Bw = cWi + (size_t)y * 128 * 128;
  const float* bias = cbi + y * 128;
  {
    const uint4* Bg = (const uint4*)Bw;
    const uint4* Ag = (const uint4*)(X + (size_t)M0 * 128);
    for (int t = tid; t < 2048; t += 512) {
      int row = t >> 4, cc = t & 15;
      *(uint4*)&As[row * 136 + cc * 8] = Ag[row * 16 + cc];
      *(uint4*)&Bs[row * 136 + cc * 8] = Bg[row * 16 + cc];
    }
  }
  __syncthreads();
  const int wave = tid >> 6, lane = tid & 63;
  const int wm = (wave >> 2) * 64, wn = (wave & 3) * 32;
  const int lr = lane & 15, kq = (lane >> 4) * 8;
  f32x4 acc[4][2] = {};
#pragma unroll
  for (int ks = 0; ks < 4; ++ks) {
    int ko = ks * 32 + kq;
    bf16x8 b0 = *(const bf16x8*)&Bs[(wn + lr) * 136 + ko];
    bf16x8 b1 = *(const bf16x8*)&Bs[(wn + 16 + lr) * 136 + ko];
#pragma unroll
    for (int tm = 0; tm < 4; ++tm) {
      bf16x8 a0 = *(const bf16x8*)&As[(wm + tm * 16 + lr) * 136 + ko];
      acc[tm][0] = __builtin_amdgcn_mfma_f32_16x16x32_bf16(a0, b0, acc[tm][0], 0, 0, 0);
      acc[tm][1] = __builtin_amdgcn_mfma_f32_16x16x32_bf16(a0, b1, acc[tm][1], 0, 0, 0);
    }
  }
  u16* outp = (y == 0) ? QB : ((y == 1) ? KB : VB);
  const float scale = (y == 0) ? 0.25f : 1.f;
  const int colq = lane & 15, rowq = (lane >> 4) * 4;
#pragma unroll
  for (int tm = 0; tm < 4; ++tm)
#pragma unroll
    for (int tn = 0; tn < 2; ++tn) {
#pragma unroll
      for (int r = 0; r < 4; ++r) {
        int row = M0 + wm + tm * 16 + rowq + r;
        int col = wn + tn * 16 + colq;
        float v = (acc[tm][tn][r] + bias[col]) * scale;
        int e = col >> 4, c = col & 15;
        int b = row & 127, pos = row >> 7;
        outp[((size_t)(b * NH + e) * W_ + pos) * HD + c] = f2bf(v);
      }
    }
}

// ---------------------------------------------------------------------------
// MFMA flash attention per (head e, batch-row b). Two-pass softmax; P stays
// in registers (sigma-permuted V); exp2 with log2e folded in.
// R13: Qsh DELETED — each wave's B-fragments only read its own 32 Q rows,
// and every fragment is a pure per-lane function of global inputs:
//   g<2: cvtpk(q*log2e) from a 16B qb load; g==2: {-i,1,1,al*L,Qhi,Qlo,0,0}
//   from ALPHA/BETA; g==3: zeros.  Same ops as the old staging -> outputs
//   bit-identical.  LDS 43264 -> 25344 B: 3 -> 4 blocks/CU (wave-capped).
// ---------------------------------------------------------------------------
__global__ __launch_bounds__(448) void attn_kernel(
    const u16* __restrict__ qb, const u16* __restrict__ kb,
    const u16* __restrict__ vb, const float* __restrict__ ALPHA,
    const float* __restrict__ BETA, const float* __restrict__ GAMMA,
    const float* __restrict__ DELTA, u16* __restrict__ obuf) {
  __shared__ u16 Ksh[224 * KSTR];
  __shared__ u16 Vt[16 * VSTR];
  const int e = blockIdx.x, b = blockIdx.y;
  const size_t hb = (size_t)(b * NH + e);
  const int tid = threadIdx.x;
  const u32 ONE = 0x3F80u;
  const float LOG2E = 1.4426950408889634f;

  if (tid < 224) {
    const int j = tid;
    const uint4* src = (const uint4*)(kb + (hb * W_ + j) * HD);
    uint4 a = src[0], b2 = src[1];
    *(uint4*)&Ksh[j * KSTR] = a;
    *(uint4*)&Ksh[j * KSTR + 8] = b2;
    float G = GAMMA[hb * 224 + j];
    float D = DELTA[hb * 224 + j];
    float jf = (float)j;
    float P = (G * jf + D) * LOG2E;
    u16 Phi = f2bf(P);
    float Plo = P - __uint_as_float((u32)Phi << 16);
    u32* ex = (u32*)&Ksh[j * KSTR + 16];
    ex[0] = (u32)f2bf(G * LOG2E) | ((u32)Phi << 16);
    ex[1] = (u32)f2bf(Plo) | ((u32)f2bf(jf) << 16);
    ex[2] = ONE | (ONE << 16);
#pragma unroll
    for (int z = 3; z < 12; ++z) ex[z] = 0;
    const uint4* vsrc = (const uint4*)(vb + (hb * W_ + j) * HD);
    uint4 va = vsrc[0], vb4 = vsrc[1];
    u32 w[8] = {va.x, va.y, va.z, va.w, vb4.x, vb4.y, vb4.z, vb4.w};
    // sigma-permuted column so PV A-fragments come straight from registers
    const int jl = j & 31;
    const int qcol = (j & ~31) | (((jl >> 2) & 3) << 3) | ((jl >> 4) << 2) | (jl & 3);
#pragma unroll
    for (int c = 0; c < 16; ++c)
      Vt[c * VSTR + qcol] = (c & 1) ? (u16)(w[c >> 1] >> 16) : (u16)(w[c >> 1] & 0xFFFF);
  }
  __syncthreads();

  const int wid = tid >> 6, lane = tid & 63;
  const int g = lane >> 4, li = lane & 15;
  const int obase = (b & 128) ? ROWS_ : 0;
  const int blow = b & 127;

  // Build both q-tiles' B-fragments in registers (loads overlap tile-0 MFMAs).
  bf16x8 BqArr[2];
#pragma unroll
  for (int t = 0; t < 2; ++t) {
    const int i = (wid * 2 + t) * 16 + li;
    uint4 o;
    if (g < 2) {
      const uint4 qa = *(const uint4*)&qb[(hb * W_ + i) * HD + g * 8];
      o.x = cvtpk(bflo(qa.x) * LOG2E, bfhi(qa.x) * LOG2E);
      o.y = cvtpk(bflo(qa.y) * LOG2E, bfhi(qa.y) * LOG2E);
      o.z = cvtpk(bflo(qa.z) * LOG2E, bfhi(qa.z) * LOG2E);
      o.w = cvtpk(bflo(qa.w) * LOG2E, bfhi(qa.w) * LOG2E);
    } else if (g == 2) {
      const float al = ALPHA[hb * 224 + i];
      const float be = BETA[hb * 224 + i];
      const float ifl = (float)i;
      const float Q = (be - al * ifl) * LOG2E;
      const u16 Qhi = f2bf(Q);
      const float Qlo = Q - __uint_as_float((u32)Qhi << 16);
      o.x = (u32)f2bf(-ifl) | (ONE << 16);
      o.y = ONE | ((u32)f2bf(al * LOG2E) << 16);
      o.z = (u32)Qhi | ((u32)f2bf(Qlo) << 16);
      o.w = 0;
    } else {
      o = make_uint4(0, 0, 0, 0);
    }
    BqArr[t] = __builtin_bit_cast(bf16x8, o);
  }

#pragma unroll
  for (int t = 0; t < 2; ++t) {
    const int qt = wid * 2 + t;
    const int i0 = qt * 16;
    const bf16x8 Bq = BqArr[t];
    f32x4 C[7][2];
#pragma unroll
    for (int js = 0; js < 7; ++js) {
      const bf16x8 A0 = *(const bf16x8*)&Ksh[(js * 32 + li) * KSTR + g * 8];
      const bf16x8 A1 = *(const bf16x8*)&Ksh[(js * 32 + 16 + li) * KSTR + g * 8];
      const f32x4 Z = {0.f, 0.f, 0.f, 0.f};
      C[js][0] = __builtin_amdgcn_mfma_f32_16x16x32_bf16(A0, Bq, Z, 0, 0, 0);
      C[js][1] = __builtin_amdgcn_mfma_f32_16x16x32_bf16(A1, Bq, Z, 0, 0, 0);
    }
    float m = -1e30f;
#pragma unroll
    for (int js = 0; js < 7; ++js)
#pragma unroll
      for (int h = 0; h < 2; ++h)
        m = fmaxf(m, fmaxf(fmaxf(C[js][h][0], C[js][h][1]), fmaxf(C[js][h][2], C[js][h][3])));
    m = fmaxf(m, __shfl_xor(m, 16));
    m = fmaxf(m, __shfl_xor(m, 32));
    f32x4 O = {0.f, 0.f, 0.f, 0.f};
    float lsum = 0.f;
#pragma unroll
    for (int js = 0; js < 7; ++js) {
      float p0 = EX2(C[js][0][0] - m), p1 = EX2(C[js][0][1] - m);
      float p2 = EX2(C[js][0][2] - m), p3 = EX2(C[js][0][3] - m);
      float p4 = EX2(C[js][1][0] - m), p5 = EX2(C[js][1][1] - m);
      float p6 = EX2(C[js][1][2] - m), p7 = EX2(C[js][1][3] - m);
      lsum += ((p0 + p1) + (p2 + p3)) + ((p4 + p5) + (p6 + p7));
      uint4 pu = make_uint4(cvtpk(p0, p1), cvtpk(p2, p3), cvtpk(p4, p5), cvtpk(p6, p7));
      const bf16x8 Ap = __builtin_bit_cast(bf16x8, pu);
      const bf16x8 Bv = *(const bf16x8*)&Vt[li * VSTR + js * 32 + g * 8];
      O = __builtin_amdgcn_mfma_f32_16x16x32_bf16(Ap, Bv, O, 0, 0, 0);
    }
    lsum += __shfl_xor(lsum, 16);
    lsum += __shfl_xor(lsum, 32);
#pragma unroll
    for (int r = 0; r < 4; ++r) {
      const float lr = __shfl(lsum, g * 4 + r);
      const int irow = i0 + g * 4 + r;
      obuf[((size_t)(obase + irow * 128 + blow)) * C_ + e * HD + li] = f2bf(O[r] * (1.f / lr));
    }
  }
}

// Gather x_l/x_r[b][c][h][w] -> bf16 rows p = img*28672 + w*128 + h*2 + b.
__global__ __launch_bounds__(256) void transpose_kernel(const float* __restrict__ x_l,
                                                        const float* __restrict__ x_r,
                                                        u16* __restrict__ xT) {
  __shared__ float tile[128][57];
  const int wt = blockIdx.x * 56, hi = blockIdx.y;
  const int img = blockIdx.z >> 1, bi = blockIdx.z & 1;
  const float* x = img ? x_r : x_l;
  const int wave = threadIdx.x >> 6, lane = threadIdx.x & 63;
  for (int c = wave; c < 128; c += 4) {
    if (lane < 56)
      tile[c][lane] = x[(((size_t)bi * 128 + c) * 64 + hi) * 224 + wt + lane];
  }
  __syncthreads();
  u32* dst = (u32*)xT;
  for (int w = wave; w < 56; w += 4) {
    int p = img * ROWS_ + (wt + w) * 128 + hi * 2 + bi;
    float a = tile[lane * 2][w], b2 = tile[lane * 2 + 1][w];
    dst[(size_t)p * 64 + lane] = (u32)f2bf(a) | ((u32)f2bf(b2) << 16);
  }
}

// ---------------------------------------------------------------------------
// Final soft-argmax, MFMA version.
// ---------------------------------------------------------------------------
__global__ __launch_bounds__(448) void corresp_kernel(
    const u16* __restrict__ qb, const u16* __restrict__ kb,
    const float* __restrict__ ALPHA, const float* __restrict__ BETA,
    const float* __restrict__ GAMMA, const float* __restrict__ DELTA,
    float* __restrict__ out) {
  __shared__ u16 Ksh[224 * 136];   // 60,928 B
  __shared__ float Gs[224], Ds[224];
  const int b = blockIdx.x, tid = threadIdx.x;
  if (tid < 224) {
    const int j = tid;
#pragma unroll
    for (int e = 0; e < 8; ++e) {
      const uint4* src = (const uint4*)(kb + ((size_t)(b * 8 + e) * 224 + j) * 16);
      *(uint4*)&Ksh[j * 136 + e * 16] = src[0];
      *(uint4*)&Ksh[j * 136 + e * 16 + 8] = src[1];
    }
    float gs = 0.f, ds = 0.f;
#pragma unroll
    for (int e = 0; e < 8; ++e) {
      gs += GAMMA[((size_t)(b * 8 + e)) * 224 + j];
      ds += DELTA[((size_t)(b * 8 + e)) * 224 + j];
    }
    Gs[j] = gs;
    Ds[j] = ds;
  }
  __syncthreads();
  const int wid = tid >> 6, lane = tid & 63;
  const int g = lane >> 4, li = lane & 15;
  const int i = blockIdx.y * 112 + wid * 16 + li;
  bf16x8 Bq[4];
#pragma unroll
  for (int ks = 0; ks < 4; ++ks) {
    const int e2 = ks * 2 + (g >> 1), c0 = (g & 1) * 8;
    Bq[ks] = *(const bf16x8*)&qb[((size_t)(b * 8 + e2) * 224 + i) * 16 + c0];
  }
  f32x4 C[14];
#pragma unroll
  for (int js = 0; js < 14; ++js) {
    f32x4 acc = {0.f, 0.f, 0.f, 0.f};
#pragma unroll
    for (int ks = 0; ks < 4; ++ks) {
      const bf16x8 A = *(const bf16x8*)&Ksh[(js * 16 + li) * 136 + ks * 32 + g * 8];
      acc = __builtin_amdgcn_mfma_f32_16x16x32_bf16(A, Bq[ks], acc, 0, 0, 0);
    }
    C[js] = acc;
  }
  float ai = 0.f, bi_ = 0.f;
#pragma unroll
  for (int e = 0; e < 8; ++e) {
    ai += ALPHA[((size_t)(b * 8 + e)) * 224 + i];
    bi_ += BETA[((size_t)(b * 8 + e)) * 224 + i];
  }
  const float ifl = (float)i;
  float m = -1e30f;
#pragma unroll
  for (int js = 0; js < 14; ++js) {
#pragma unroll
    for (int r = 0; r < 4; ++r) {
      const int j = js * 16 + g * 4 + r;
      float s = C[js][r] + ((float)j - ifl) * (ai + Gs[j]) + bi_ + Ds[j];
      C[js][r] = s;
      m = fmaxf(m, s);
    }
  }
  m = fmaxf(m, __shfl_xor(m, 16));
  m = fmaxf(m, __shfl_xor(m, 32));
  float l = 0.f, wj = 0.f;
#pragma unroll
  for (int js = 0; js < 14; ++js) {
#pragma unroll
    for (int r = 0; r < 4; ++r) {
      const float p = __expf(C[js][r] - m);
      l += p;
      wj += p * (float)(js * 16 + g * 4 + r);
    }
  }
  l += __shfl_xor(l, 16);
  l += __shfl_xor(l, 32);
  wj += __shfl_xor(wj, 16);
  wj += __shfl_xor(wj, 32);
  if (g == 0) out[(size_t)b * 224 + i] = ifl - wj / fmaxf(l, 1e-30f);
}

// Single-launch conversion of all five weight tensors to one bf16 buffer.
#define OFF_FEAT 0
#define OFF_SWI 16384
#define OFF_SWO 311296
#define OFF_CWI 409600
#define OFF_CWO 704512
#define N_WALL 802816
__global__ __launch_bounds__(256) void cvt_all_kernel(
    const float* __restrict__ feat_w, const float* __restrict__ self_Wi,
    const float* __restrict__ self_Wo, const float* __restrict__ cross_Wi,
    const float* __restrict__ cross_Wo, u16* __restrict__ dst) {
  int idx = blockIdx.x * 256 + threadIdx.x;
  if (idx >= N_WALL) return;
  float v;
  if (idx < OFF_SWI)       v = feat_w[idx];
  else if (idx < OFF_SWO)  v = self_Wi[idx - OFF_SWI];
  else if (idx < OFF_CWI)  v = self_Wo[idx - OFF_SWO];
  else if (idx < OFF_CWO)  v = cross_Wi[idx - OFF_CWI];
  else                     v = cross_Wo[idx - OFF_CWO];
  dst[idx] = f2bf(v);
}

extern "C" void kernel_launch(void* const* d_in, const int* in_sizes, int n_in,
                              void* d_out, int out_size, void* d_ws, size_t ws_size,
                              hipStream_t stream) {
  (void)in_sizes; (void)n_in; (void)out_size; (void)ws_size;
  const float* x_l = (const float*)d_in[0];
  const float* x_r = (const float*)d_in[1];
  const float* feat_w = (const float*)d_in[2];
  const float* feat_b = (const float*)d_in[3];
  const float* self_Wi = (const float*)d_in[4];
  const float* self_bi = (const float*)d_in[5];
  const float* self_Wo = (const float*)d_in[6];
  const float* self_bo = (const float*)d_in[7];
  const float* cross_Wi = (const float*)d_in[8];
  const float* cross_bi = (const float*)d_in[9];
  const float* cross_Wo = (const float*)d_in[10];
  const float* cross_bo = (const float*)d_in[11];
  const float* ln_g = (const float*)d_in[12];
  const float* ln_b = (const float*)d_in[13];

  char* ws = (char*)d_ws;
  size_t off = 0;
  auto alloc = [&](size_t bytes) {
    char* p = ws + off;
    off += (bytes + 255) & ~(size_t)255;
    return p;
  };
  // Total ~97 MB — under the R6-proven ~112 MB budget. XB aliases OB:
  // XB live range is tab->qkv, OB live range is attn->out-proj (disjoint).
  float* XA = (float*)alloc((size_t)2 * ROWS_ * C_ * 4);   // residual (in-place LN)
  u16* QB = (u16*)alloc((size_t)256 * NH * W_ * HD * 2);   // also XT scratch
  u16* KB = (u16*)alloc((size_t)256 * NH * W_ * HD * 2);
  u16* VB = (u16*)alloc((size_t)256 * NH * W_ * HD * 2);
  u16* OB = (u16*)alloc((size_t)2 * ROWS_ * C_ * 2);
  u16* WALL = (u16*)alloc((size_t)N_WALL * 2);
  float* PREP = (float*)alloc((size_t)12 * PREP_STRIDE * 4);
  float* ALPHA = (float*)alloc((size_t)256 * NH * W_ * 4);
  float* BETA = (float*)alloc((size_t)256 * NH * W_ * 4);
  float* GAMMA = (float*)alloc((size_t)256 * NH * W_ * 4);
  float* DELTA = (float*)alloc((size_t)256 * NH * W_ * 4);
  u16* XB = OB;   // alias — disjoint live ranges

  cvt_all_kernel<<<3136, 256, 0, stream>>>(feat_w, self_Wi, self_Wo, cross_Wi, cross_Wo, WALL);
  prep_kernel<<<dim3(12, 8), 256, 0, stream>>>(self_Wi, self_bi, cross_Wi, cross_bi, PREP);

  transpose_kernel<<<dim3(4, 64, 4), 256, 0, stream>>>(x_l, x_r, QB);
  gemm_plain<<<dim3(896, 2), 256, 0, stream>>>(QB, WALL + OFF_FEAT, feat_b, 5, XA);

  for (int l = 0; l < 6; ++l) {
    const u16* sWi = WALL + OFF_SWI + (size_t)l * 384 * 128;
    const u16* sWo = WALL + OFF_SWO + (size_t)l * 128 * 128;
    const u16* cWi = WALL + OFF_CWI + (size_t)l * 384 * 128;
    const u16* cWo = WALL + OFF_CWO + (size_t)l * 128 * 128;
    const float* sbi = self_bi + l * 384;
    const float* sbo = self_bo + l * 128;
    const float* cbi = cross_bi + l * 384;
    const float* cbo = cross_bo + l * 128;
    const float* ps = PREP + (size_t)(l * 2) * PREP_STRIDE;
    const float* pc = PREP + (size_t)(l * 2 + 1) * PREP_STRIDE;

    // --- self attention on xl AND xr: X = LN(X) (+tables+XB), qkv, attn, +=proj ---
    tab_kernel<<<1792, 256, 0, stream>>>(XA, ln_g, ln_b, ps, ps + 4096, ALPHA, BETA,
                                         ps + 2048, ps + 4112, GAMMA, DELTA, XB, 0);
    gemm_qkv_self<<<dim3(448, 3), 512, 0, stream>>>(XB, sWi, sbi, QB, KB, VB);
    attn_kernel<<<dim3(8, 256), 448, 0, stream>>>(QB, KB, VB, ALPHA, BETA, GAMMA, DELTA, OB);
    gemm_plain<<<dim3(896, 2), 256, 0, stream>>>(OB, sWo, sbo, 4, XA);

    // --- cross attention: q from xr, k/v from xl; X = LN(X) first ---
    tab_kernel<<<1792, 256, 0, stream>>>(XA, ln_g, ln_b, pc, pc + 4096, ALPHA, BETA,
                                         pc + 2048, pc + 4112, GAMMA, DELTA, XB, 1);
    // l==5: V (y=2) is dead — no attn launch follows and corresp reads QB/KB only.
    gemm_qkv_cross<<<dim3(224, (l < 5) ? 3 : 2), 512, 0, stream>>>(
        XB, XB + (size_t)ROWS_ * C_, cWi, cbi, QB, KB, VB);
    if (l < 5) {
      attn_kernel<<<dim3(8, 128), 448, 0, stream>>>(QB, KB, VB, ALPHA, BETA, GAMMA, DELTA, OB);
      gemm_plain<<<dim3(448, 2), 256, 0, stream>>>(OB, cWo, cbo, 4, XA);  // xl half only
    }
    // l == 5: attention output / x updates dead; corresp reads QB/KB + tables.
  }
  corresp_kernel<<<dim3(128, 2), 448, 0, stream>>>(QB, KB, ALPHA, BETA, GAMMA, DELTA,
                                                   (float*)d_out);
}

// Round 14
// 1142.931 us; speedup vs baseline: 1.0173x; 1.0066x over previous
//
#include <hip/hip_runtime.h>

typedef unsigned short u16;
typedef unsigned int u32;

#define W_ 224
#define H_ 128
#define C_ 128
#define NH 8
#define HD 16
#define ROWS_ (W_ * H_)          // 28672 rows per image
#define PREP_STRIDE 4128
#define KSTR 40
#define VSTR 232
#define TROWS 32                 // rows per tab_kernel block

typedef __bf16 bf16x8 __attribute__((ext_vector_type(8)));
typedef float f32x4 __attribute__((ext_vector_type(4)));

__device__ __forceinline__ u16 f2bf(float f) {
  u32 u = __float_as_uint(f);
  return (u16)((u + 0x7FFFu + ((u >> 16) & 1u)) >> 16);
}
// Packed RNE f32->bf16 pair: single v_cvt_pk_bf16_f32 (same rounding as f2bf).
__device__ __forceinline__ u32 cvtpk(float lo, float hi) {
  u32 r;
  asm("v_cvt_pk_bf16_f32 %0, %1, %2" : "=v"(r) : "v"(lo), "v"(hi));
  return r;
}
__device__ __forceinline__ float bflo(u32 u) { return __uint_as_float(u << 16); }
__device__ __forceinline__ float bfhi(u32 u) { return __uint_as_float(u & 0xFFFF0000u); }

#if __has_builtin(__builtin_amdgcn_exp2f)
#define EX2(x) __builtin_amdgcn_exp2f(x)
#else
#define EX2(x) __expf((x) * 0.6931471805599453f)
#endif

// ---------------------------------------------------------------------------
// Rank-1 PE decomposition prep: grid (12 s, 8 e-groups), LDS-staged, coalesced.
// ---------------------------------------------------------------------------
__global__ __launch_bounds__(256) void prep_kernel(
    const float* __restrict__ self_Wi, const float* __restrict__ self_bi,
    const float* __restrict__ cross_Wi, const float* __restrict__ cross_bi,
    float* __restrict__ prep) {
  __shared__ float Wq[16][132];
  __shared__ float Wk[16][132];
  __shared__ float u[128];
  __shared__ float Aq[16], Ak[16], bq[16], bk[16];
  const int s = blockIdx.x, e = blockIdx.y, l = s >> 1;
  const float* Wi = (s & 1) ? cross_Wi + (size_t)l * 384 * 128 : self_Wi + (size_t)l * 384 * 128;
  const float* bi = (s & 1) ? cross_bi + l * 384 : self_bi + l * 384;
  const int tid = threadIdx.x;
  if (tid < 128) {
    float ex = (float)(tid & ~1) * (1.f / 128.f);
    u[tid] = expf(-ex * logf(10000.f));
  }
  if (tid >= 128 && tid < 144) { int r = tid - 128; bq[r] = bi[e * 16 + r]; }
  if (tid >= 160 && tid < 176) { int r = tid - 160; bk[r] = bi[128 + e * 16 + r]; }
  for (int t = tid; t < 2048; t += 256) {
    int r = t >> 7, f = t & 127;
    Wq[r][f] = Wi[(size_t)(e * 16 + r) * 128 + f];
    Wk[r][f] = Wi[(size_t)(128 + e * 16 + r) * 128 + f];
  }
  __syncthreads();
  {
    const int grp = tid >> 3;
    const int lg = tid & 7;
    const float* row = (grp < 16) ? Wq[grp] : Wk[grp - 16];
    float a = 0.f;
#pragma unroll
    for (int i = 0; i < 16; ++i) a += row[lg * 16 + i] * u[lg * 16 + i];
    a += __shfl_xor(a, 1);
    a += __shfl_xor(a, 2);
    a += __shfl_xor(a, 4);
    if (lg == 0) {
      if (grp < 16) Aq[grp] = a;
      else          Ak[grp - 16] = a;
    }
  }
  __syncthreads();
  float* out = prep + (size_t)s * PREP_STRIDE;
  for (int t = tid; t < 512; t += 256) {
    int v = t >> 7, f = t & 127;
    float acc = 0.f;
#pragma unroll
    for (int c = 0; c < 16; ++c) {
      if (v == 0)      acc += Wq[c][f] * Ak[c];
      else if (v == 1) acc += Wq[c][f] * bk[c];
      else if (v == 2) acc += Wk[c][f] * Aq[c];
      else             acc += Wk[c][f] * bq[c];
    }
    out[v * 1024 + e * 128 + f] = acc * 0.25f;
  }
  if (tid < 4) {
    int v = tid;
    float acc = 0.f;
#pragma unroll
    for (int c = 0; c < 16; ++c) {
      if (v == 0)      acc += bq[c] * Ak[c];
      else if (v == 1) acc += bq[c] * bk[c];
      else if (v == 2) acc += bk[c] * Aq[c];
      else             acc += bk[c] * bq[c];
    }
    out[4096 + v * 8 + e] = acc * 0.25f;
  }
}

// ---------------------------------------------------------------------------
// Fused LN + affine-PE tables, 32 rows per block (R10-verified). Phase-2:
// 2x2 map; 128 b128 reads per 4 outputs; tables bit-identical.
// ---------------------------------------------------------------------------
__global__ __launch_bounds__(256) void tab_kernel(
    float* __restrict__ x, const float* __restrict__ g,
    const float* __restrict__ b, const float* __restrict__ wq,
    const float* __restrict__ cq, float* __restrict__ outA, float* __restrict__ outB,
    const float* __restrict__ wk, const float* __restrict__ ck,
    float* __restrict__ outG, float* __restrict__ outD,
    u16* __restrict__ xb, int mode) {
  __shared__ float ys[TROWS][132];
  __shared__ float ws[32][132];
  const int tid = threadIdx.x;
  for (int t = tid; t < 2048; t += 256) ws[t >> 7][t & 127] = wq[t];
  for (int t = tid; t < 2048; t += 256) ws[16 + (t >> 7)][t & 127] = wk[t];
  const int wv = tid >> 6, lane = tid & 63;
  const int base = blockIdx.x * TROWS;
  {
    float2 gg = ((const float2*)g)[lane];
    float2 bb = ((const float2*)b)[lane];
    // batch the 8 row loads (independent, in flight together)
    float2 vv[8];
#pragma unroll
    for (int t = 0; t < 8; ++t) {
      const int r = wv * 8 + t;
      vv[t] = ((const float2*)(x + (size_t)(base + r) * 128))[lane];
    }
    // 8 independent reduce+write chains; compiler interleaves across VALU
#pragma unroll
    for (int t = 0; t < 8; ++t) {
      const int r = wv * 8 + t;
      float2 v = vv[t];
      float s1 = v.x + v.y, s2 = v.x * v.x + v.y * v.y;
#pragma unroll
      for (int k = 1; k < 64; k <<= 1) {
        s1 += __shfl_xor(s1, k);
        s2 += __shfl_xor(s2, k);
      }
      float mean = s1 * (1.f / 128.f);
      float var = s2 * (1.f / 128.f) - mean * mean;
      float rstd = rsqrtf(var + 1e-5f);
      float y0 = (v.x - mean) * rstd * gg.x + bb.x;
      float y1 = (v.y - mean) * rstd * gg.y + bb.y;
      ((float2*)(x + (size_t)(base + r) * 128))[lane] = make_float2(y0, y1);
      ((u32*)xb)[(size_t)(base + r) * 64 + lane] = cvtpk(y0, y1);
      ys[r][2 * lane] = y0;
      ys[r][2 * lane + 1] = y1;
    }
  }
  __syncthreads();
  // 2x2 remap: thread (c2 = tid&15, rg2 = tid>>4) owns cols {2c2,2c2+1},
  // rows {2rg2, 2rg2+1}. 16x16 threads cover 32x32 outputs.
  const int c2 = tid & 15;
  const int rg2 = tid >> 4;
  const int c0 = c2 * 2;
  const int row0 = rg2 * 2;
  const int side = c0 >> 4;              // same for both cols (even start)
  const int val = (c0 & 15) >> 3;        // same for both cols
  const int e0 = c0 & 7, e1 = (c0 + 1) & 7;
  const float cadd0 = side ? ck[val * 8 + e0] : cq[val * 8 + e0];
  const float cadd1 = side ? ck[val * 8 + e1] : cq[val * 8 + e1];
  float* dst = side ? (val ? outD : outG) : (val ? outB : outA);
  // rows never straddle ROWS_ (28672 = 896*32): half uniform per block
  const int pbase = base + row0;
  const int half = (pbase >= ROWS_) ? 1 : 0;
  const bool active = (mode == 0) || (half ? (side == 0) : (side == 1));
  if (active) {
    const float4* w0 = (const float4*)&ws[c0][0];
    const float4* w1 = (const float4*)&ws[c0 + 1][0];
    const float4* y0 = (const float4*)&ys[row0][0];
    const float4* y1 = (const float4*)&ys[row0 + 1][0];
    float4 s00 = {0.f, 0.f, 0.f, 0.f}, s01 = s00, s10 = s00, s11 = s00;
#pragma unroll 4
    for (int f4 = 0; f4 < 32; ++f4) {
      float4 wa = w0[f4], wb = w1[f4];
      float4 ya = y0[f4], yb = y1[f4];
      s00.x += ya.x * wa.x; s00.y += ya.y * wa.y; s00.z += ya.z * wa.z; s00.w += ya.w * wa.w;
      s01.x += ya.x * wb.x; s01.y += ya.y * wb.y; s01.z += ya.z * wb.z; s01.w += ya.w * wb.w;
      s10.x += yb.x * wa.x; s10.y += yb.y * wa.y; s10.z += yb.z * wa.z; s10.w += yb.w * wa.w;
      s11.x += yb.x * wb.x; s11.y += yb.y * wb.y; s11.z += yb.z * wb.z; s11.w += yb.w * wb.w;
    }
    const float a00 = (s00.x + s00.y) + (s00.z + s00.w);
    const float a01 = (s01.x + s01.y) + (s01.z + s01.w);
    const float a10 = (s10.x + s10.y) + (s10.z + s10.w);
    const float a11 = (s11.x + s11.y) + (s11.z + s11.w);
#pragma unroll
    for (int rr = 0; rr < 2; ++rr) {
      const int ploc = pbase + rr - half * ROWS_;
      const int i = ploc >> 7, blow = ploc & 127;
      const int b_out = (mode == 0) ? half * 128 + blow : blow;
      const float v0 = (rr == 0) ? a00 : a10;
      const float v1 = (rr == 0) ? a01 : a11;
      dst[((size_t)(b_out * 8 + e0)) * 224 + i] = v0 + cadd0;
      dst[((size_t)(b_out * 8 + e1)) * 224 + i] = v1 + cadd1;
    }
  }
}

// ---------------------------------------------------------------------------
// Plain 64x64-tile bf16 MFMA GEMM (bf16 A input) — R3-verified version.
// mode 4: fout += acc + bias (out-proj residual); mode 5: fout = acc + bias.
// ---------------------------------------------------------------------------
__global__ __launch_bounds__(256) void gemm_plain(
    const u16* __restrict__ A, const u16* __restrict__ B,
    const float* __restrict__ bias, int mode, float* __restrict__ fout) {
  __shared__ u16 As[64 * 136];
  __shared__ u16 Bs[64 * 136];
  const int tid = threadIdx.x;
  const int M0 = blockIdx.x * 64, N0 = blockIdx.y * 64;
  const uint4* Ag = (const uint4*)(A + (size_t)M0 * 128);
  const uint4* Bg = (const uint4*)(B + (size_t)N0 * 128);
  for (int t = tid; t < 1024; t += 256) {
    int row = t >> 4, cc = t & 15;
    *(uint4*)&As[row * 136 + cc * 8] = Ag[row * 16 + cc];
  }
  for (int t = tid; t < 1024; t += 256) {
    int row = t >> 4, cc = t & 15;
    *(uint4*)&Bs[row * 136 + cc * 8] = Bg[row * 16 + cc];
  }
  __syncthreads();
  const int wave = tid >> 6, lane = tid & 63;
  const int wm = (wave >> 1) * 32, wn = (wave & 1) * 32;
  const int lr = lane & 15, kq = (lane >> 4) * 8;
  f32x4 acc[2][2] = {};
#pragma unroll
  for (int ks = 0; ks < 4; ++ks) {
    int ko = ks * 32 + kq;
    bf16x8 a0 = *(const bf16x8*)&As[(wm + lr) * 136 + ko];
    bf16x8 a1 = *(const bf16x8*)&As[(wm + 16 + lr) * 136 + ko];
    bf16x8 b0 = *(const bf16x8*)&Bs[(wn + lr) * 136 + ko];
    bf16x8 b1 = *(const bf16x8*)&Bs[(wn + 16 + lr) * 136 + ko];
    acc[0][0] = __builtin_amdgcn_mfma_f32_16x16x32_bf16(a0, b0, acc[0][0], 0, 0, 0);
    acc[0][1] = __builtin_amdgcn_mfma_f32_16x16x32_bf16(a0, b1, acc[0][1], 0, 0, 0);
    acc[1][0] = __builtin_amdgcn_mfma_f32_16x16x32_bf16(a1, b0, acc[1][0], 0, 0, 0);
    acc[1][1] = __builtin_amdgcn_mfma_f32_16x16x32_bf16(a1, b1, acc[1][1], 0, 0, 0);
  }
  const int colq = lane & 15, rowq = (lane >> 4) * 4;
#pragma unroll
  for (int tm = 0; tm < 2; ++tm)
#pragma unroll
    for (int tn = 0; tn < 2; ++tn) {
#pragma unroll
      for (int r = 0; r < 4; ++r) {
        int row = M0 + wm + tm * 16 + rowq + r;
        int col = N0 + wn + tn * 16 + colq;
        float v = acc[tm][tn][r] + bias[col];
        if (mode == 4) fout[(size_t)row * 128 + col] += v;
        else           fout[(size_t)row * 128 + col] = v;
      }
    }
}

// ---------------------------------------------------------------------------
// Self QKV GEMM: 128x128 tiles, 512 threads (8 waves, each 64x32). A from XB.
// ---------------------------------------------------------------------------
__global__ __launch_bounds__(512) void gemm_qkv_self(
    const u16* __restrict__ X, const u16* __restrict__ Bw,
    const float* __restrict__ bias, u16* __restrict__ o0, u16* __restrict__ o1,
    u16* __restrict__ o2) {
  __shared__ u16 As[128 * 136];
  __shared__ u16 Bs[128 * 136];
  const int tid = threadIdx.x;
  const int M0 = blockIdx.x * 128, N0 = blockIdx.y * 128;
  {
    const uint4* Bg = (const uint4*)(Bw + (size_t)N0 * 128);
    const uint4* Ag = (const uint4*)(X + (size_t)M0 * 128);
    for (int t = tid; t < 2048; t += 512) {
      int row = t >> 4, cc = t & 15;
      *(uint4*)&As[row * 136 + cc * 8] = Ag[row * 16 + cc];
      *(uint4*)&Bs[row * 136 + cc * 8] = Bg[row * 16 + cc];
    }
  }
  __syncthreads();
  const int wave = tid >> 6, lane = tid & 63;
  const int wm = (wave >> 2) * 64, wn = (wave & 3) * 32;
  const int lr = lane & 15, kq = (lane >> 4) * 8;
  f32x4 acc[4][2] = {};
#pragma unroll
  for (int ks = 0; ks < 4; ++ks) {
    int ko = ks * 32 + kq;
    bf16x8 b0 = *(const bf16x8*)&Bs[(wn + lr) * 136 + ko];
    bf16x8 b1 = *(const bf16x8*)&Bs[(wn + 16 + lr) * 136 + ko];
#pragma unroll
    for (int tm = 0; tm < 4; ++tm) {
      bf16x8 a0 = *(const bf16x8*)&As[(wm + tm * 16 + lr) * 136 + ko];
      acc[tm][0] = __builtin_amdgcn_mfma_f32_16x16x32_bf16(a0, b0, acc[tm][0], 0, 0, 0);
      acc[tm][1] = __builtin_amdgcn_mfma_f32_16x16x32_bf16(a0, b1, acc[tm][1], 0, 0, 0);
    }
  }
  const int colq = lane & 15, rowq = (lane >> 4) * 4;
#pragma unroll
  for (int tm = 0; tm < 4; ++tm)
#pragma unroll
    for (int tn = 0; tn < 2; ++tn) {
#pragma unroll
      for (int r = 0; r < 4; ++r) {
        int row = M0 + wm + tm * 16 + rowq + r;
        int col = N0 + wn + tn * 16 + colq;
        float v = acc[tm][tn][r] + bias[col];
        int part = col >> 7;
        int cc = col & 127;
        int e = cc >> 4, c = cc & 15;
        int rloc = row, badd = 0;
        if (row >= ROWS_) { rloc = row - ROWS_; badd = 128; }
        int b = (rloc & 127) + badd, pos = rloc >> 7;
        size_t off = ((size_t)(b * NH + e) * W_ + pos) * HD + c;
        if (part == 0)      o0[off] = f2bf(v * 0.25f);
        else if (part == 1) o1[off] = f2bf(v);
        else                o2[off] = f2bf(v);
      }
    }
}

// ---------------------------------------------------------------------------
// Cross QKV GEMM: 128x128 tiles, 512 threads.
// y=0: q from Xr (*0.25); y=1: K from Xl; y=2: V from Xl.
// At l=5 launched with grid.y=2 (V dead: no attn launch, corresp reads Q/K).
// ---------------------------------------------------------------------------
__global__ __launch_bounds__(512) void gemm_qkv_cross(
    const u16* __restrict__ Xl, const u16* __restrict__ Xr,
    const u16* __restrict__ cWi, const float* __restrict__ cbi,
    u16* __restrict__ QB, u16* __restrict__ KB, u16* __restrict__ VB) {
  __shared__ u16 As[128 * 136];
  __shared__ u16 Bs[128 * 136];
  const int tid = threadIdx.x;
  const int M0 = blockIdx.x * 128;
  const int y = blockIdx.y;
  const u16* X = (y == 0) ? Xr : Xl;
  const u16* Bw = cWi + (size_t)y * 128 * 128;
  const float* bias = cbi + y * 128;
  {
    const uint4* Bg = (const uint4*)Bw;
    const uint4* Ag = (const uint4*)(X + (size_t)M0 * 128);
    for (int t = tid; t < 2048; t += 512) {
      int row = t >> 4, cc = t & 15;
      *(uint4*)&As[row * 136 + cc * 8] = Ag[row * 16 + cc];
      *(uint4*)&Bs[row * 136 + cc * 8] = Bg[row * 16 + cc];
    }
  }
  __syncthreads();
  const int wave = tid >> 6, lane = tid & 63;
  const int wm = (wave >> 2) * 64, wn = (wave & 3) * 32;
  const int lr = lane & 15, kq = (lane >> 4) * 8;
  f32x4 acc[4][2] = {};
#pragma unroll
  for (int ks = 0; ks < 4; ++ks) {
    int ko = ks * 32 + kq;
    bf16x8 b0 = *(const bf16x8*)&Bs[(wn + lr) * 136 + ko];
    bf16x8 b1 = *(const bf16x8*)&Bs[(wn + 16 + lr) * 136 + ko];
#pragma unroll
    for (int tm = 0; tm < 4; ++tm) {
      bf16x8 a0 = *(const bf16x8*)&As[(wm + tm * 16 + lr) * 136 + ko];
      acc[tm][0] = __builtin_amdgcn_mfma_f32_16x16x32_bf16(a0, b0, acc[tm][0], 0, 0, 0);
      acc[tm][1] = __builtin_amdgcn_mfma_f32_16x16x32_bf16(a0, b1, acc[tm][1], 0, 0, 0);
    }
  }
  u16* outp = (y == 0) ? QB : ((y == 1) ? KB : VB);
  const float scale = (y == 0) ? 0.25f : 1.f;
  const int colq = lane & 15, rowq = (lane >> 4) * 4;
#pragma unroll
  for (int tm = 0; tm < 4; ++tm)
#pragma unroll
    for (int tn = 0; tn < 2; ++tn) {
#pragma unroll
      for (int r = 0; r < 4; ++r) {
        int row = M0 + wm + tm * 16 + rowq + r;
        int col = wn + tn * 16 + colq;
        float v = (acc[tm][tn][r] + bias[col]) * scale;
        int e = col >> 4, c = col & 15;
        int b = row & 127, pos = row >> 7;
        outp[((size_t)(b * NH + e) * W_ + pos) * HD + c] = f2bf(v);
      }
    }
}

// ---------------------------------------------------------------------------
// MFMA flash attention per (head e, batch-row b). Two-pass softmax; P stays
// in registers (sigma-permuted V); exp2 with log2e folded in; Qsh deleted
// (Q fragments built per-lane in registers — R13).
// R14: staging split across all 448 threads — K row + ex-word on tid<224,
// V load + sigma scatter on tid in [224,448) (j = tid-224). Same writes,
// disjoint LDS ranges (Ksh vs Vt), all before the same barrier -> outputs
// bit-identical; staging critical path = max(K-path, V-path), not their sum
// (old code: tid<224 did K+ex+V serially while tid>=224 idled).
// ---------------------------------------------------------------------------
__global__ __launch_bounds__(448) void attn_kernel(
    const u16* __restrict__ qb, const u16* __restrict__ kb,
    const u16* __restrict__ vb, const float* __restrict__ ALPHA,
    const float* __restrict__ BETA, const float* __restrict__ GAMMA,
    const float* __restrict__ DELTA, u16* __restrict__ obuf) {
  __shared__ u16 Ksh[224 * KSTR];
  __shared__ u16 Vt[16 * VSTR];
  const int e = blockIdx.x, b = blockIdx.y;
  const size_t hb = (size_t)(b * NH + e);
  const int tid = threadIdx.x;
  const u32 ONE = 0x3F80u;
  const float LOG2E = 1.4426950408889634f;

  if (tid < 224) {
    const int j = tid;
    const uint4* src = (const uint4*)(kb + (hb * W_ + j) * HD);
    uint4 a = src[0], b2 = src[1];
    *(uint4*)&Ksh[j * KSTR] = a;
    *(uint4*)&Ksh[j * KSTR + 8] = b2;
    float G = GAMMA[hb * 224 + j];
    float D = DELTA[hb * 224 + j];
    float jf = (float)j;
    float P = (G * jf + D) * LOG2E;
    u16 Phi = f2bf(P);
    float Plo = P - __uint_as_float((u32)Phi << 16);
    u32* ex = (u32*)&Ksh[j * KSTR + 16];
    ex[0] = (u32)f2bf(G * LOG2E) | ((u32)Phi << 16);
    ex[1] = (u32)f2bf(Plo) | ((u32)f2bf(jf) << 16);
    ex[2] = ONE | (ONE << 16);
#pragma unroll
    for (int z = 3; z < 12; ++z) ex[z] = 0;
  } else {
    const int j = tid - 224;
    const uint4* vsrc = (const uint4*)(vb + (hb * W_ + j) * HD);
    uint4 va = vsrc[0], vb4 = vsrc[1];
    u32 w[8] = {va.x, va.y, va.z, va.w, vb4.x, vb4.y, vb4.z, vb4.w};
    // sigma-permuted column so PV A-fragments come straight from registers
    const int jl = j & 31;
    const int qcol = (j & ~31) | (((jl >> 2) & 3) << 3) | ((jl >> 4) << 2) | (jl & 3);
#pragma unroll
    for (int c = 0; c < 16; ++c)
      Vt[c * VSTR + qcol] = (c & 1) ? (u16)(w[c >> 1] >> 16) : (u16)(w[c >> 1] & 0xFFFF);
  }
  __syncthreads();

  const int wid = tid >> 6, lane = tid & 63;
  const int g = lane >> 4, li = lane & 15;
  const int obase = (b & 128) ? ROWS_ : 0;
  const int blow = b & 127;

  // Build both q-tiles' B-fragments in registers (loads overlap tile-0 MFMAs).
  bf16x8 BqArr[2];
#pragma unroll
  for (int t = 0; t < 2; ++t) {
    const int i = (wid * 2 + t) * 16 + li;
    uint4 o;
    if (g < 2) {
      const uint4 qa = *(const uint4*)&qb[(hb * W_ + i) * HD + g * 8];
      o.x = cvtpk(bflo(qa.x) * LOG2E, bfhi(qa.x) * LOG2E);
      o.y = cvtpk(bflo(qa.y) * LOG2E, bfhi(qa.y) * LOG2E);
      o.z = cvtpk(bflo(qa.z) * LOG2E, bfhi(qa.z) * LOG2E);
      o.w = cvtpk(bflo(qa.w) * LOG2E, bfhi(qa.w) * LOG2E);
    } else if (g == 2) {
      const float al = ALPHA[hb * 224 + i];
      const float be = BETA[hb * 224 + i];
      const float ifl = (float)i;
      const float Q = (be - al * ifl) * LOG2E;
      const u16 Qhi = f2bf(Q);
      const float Qlo = Q - __uint_as_float((u32)Qhi << 16);
      o.x = (u32)f2bf(-ifl) | (ONE << 16);
      o.y = ONE | ((u32)f2bf(al * LOG2E) << 16);
      o.z = (u32)Qhi | ((u32)f2bf(Qlo) << 16);
      o.w = 0;
    } else {
      o = make_uint4(0, 0, 0, 0);
    }
    BqArr[t] = __builtin_bit_cast(bf16x8, o);
  }

#pragma unroll
  for (int t = 0; t < 2; ++t) {
    const int qt = wid * 2 + t;
    const int i0 = qt * 16;
    const bf16x8 Bq = BqArr[t];
    f32x4 C[7][2];
#pragma unroll
    for (int js = 0; js < 7; ++js) {
      const bf16x8 A0 = *(const bf16x8*)&Ksh[(js * 32 + li) * KSTR + g * 8];
      const bf16x8 A1 = *(const bf16x8*)&Ksh[(js * 32 + 16 + li) * KSTR + g * 8];
      const f32x4 Z = {0.f, 0.f, 0.f, 0.f};
      C[js][0] = __builtin_amdgcn_mfma_f32_16x16x32_bf16(A0, Bq, Z, 0, 0, 0);
      C[js][1] = __builtin_amdgcn_mfma_f32_16x16x32_bf16(A1, Bq, Z, 0, 0, 0);
    }
    float m = -1e30f;
#pragma unroll
    for (int js = 0; js < 7; ++js)
#pragma unroll
      for (int h = 0; h < 2; ++h)
        m = fmaxf(m, fmaxf(fmaxf(C[js][h][0], C[js][h][1]), fmaxf(C[js][h][2], C[js][h][3])));
    m = fmaxf(m, __shfl_xor(m, 16));
    m = fmaxf(m, __shfl_xor(m, 32));
    f32x4 O = {0.f, 0.f, 0.f, 0.f};
    float lsum = 0.f;
#pragma unroll
    for (int js = 0; js < 7; ++js) {
      float p0 = EX2(C[js][0][0] - m), p1 = EX2(C[js][0][1] - m);
      float p2 = EX2(C[js][0][2] - m), p3 = EX2(C[js][0][3] - m);
      float p4 = EX2(C[js][1][0] - m), p5 = EX2(C[js][1][1] - m);
      float p6 = EX2(C[js][1][2] - m), p7 = EX2(C[js][1][3] - m);
      lsum += ((p0 + p1) + (p2 + p3)) + ((p4 + p5) + (p6 + p7));
      uint4 pu = make_uint4(cvtpk(p0, p1), cvtpk(p2, p3), cvtpk(p4, p5), cvtpk(p6, p7));
      const bf16x8 Ap = __builtin_bit_cast(bf16x8, pu);
      const bf16x8 Bv = *(const bf16x8*)&Vt[li * VSTR + js * 32 + g * 8];
      O = __builtin_amdgcn_mfma_f32_16x16x32_bf16(Ap, Bv, O, 0, 0, 0);
    }
    lsum += __shfl_xor(lsum, 16);
    lsum += __shfl_xor(lsum, 32);
#pragma unroll
    for (int r = 0; r < 4; ++r) {
      const float lr = __shfl(lsum, g * 4 + r);
      const int irow = i0 + g * 4 + r;
      obuf[((size_t)(obase + irow * 128 + blow)) * C_ + e * HD + li] = f2bf(O[r] * (1.f / lr));
    }
  }
}

// Gather x_l/x_r[b][c][h][w] -> bf16 rows p = img*28672 + w*128 + h*2 + b.
__global__ __launch_bounds__(256) void transpose_kernel(const float* __restrict__ x_l,
                                                        const float* __restrict__ x_r,
                                                        u16* __restrict__ xT) {
  __shared__ float tile[128][57];
  const int wt = blockIdx.x * 56, hi = blockIdx.y;
  const int img = blockIdx.z >> 1, bi = blockIdx.z & 1;
  const float* x = img ? x_r : x_l;
  const int wave = threadIdx.x >> 6, lane = threadIdx.x & 63;
  for (int c = wave; c < 128; c += 4) {
    if (lane < 56)
      tile[c][lane] = x[(((size_t)bi * 128 + c) * 64 + hi) * 224 + wt + lane];
  }
  __syncthreads();
  u32* dst = (u32*)xT;
  for (int w = wave; w < 56; w += 4) {
    int p = img * ROWS_ + (wt + w) * 128 + hi * 2 + bi;
    float a = tile[lane * 2][w], b2 = tile[lane * 2 + 1][w];
    dst[(size_t)p * 64 + lane] = (u32)f2bf(a) | ((u32)f2bf(b2) << 16);
  }
}

// ---------------------------------------------------------------------------
// Final soft-argmax, MFMA version.
// ---------------------------------------------------------------------------
__global__ __launch_bounds__(448) void corresp_kernel(
    const u16* __restrict__ qb, const u16* __restrict__ kb,
    const float* __restrict__ ALPHA, const float* __restrict__ BETA,
    const float* __restrict__ GAMMA, const float* __restrict__ DELTA,
    float* __restrict__ out) {
  __shared__ u16 Ksh[224 * 136];   // 60,928 B
  __shared__ float Gs[224], Ds[224];
  const int b = blockIdx.x, tid = threadIdx.x;
  if (tid < 224) {
    const int j = tid;
#pragma unroll
    for (int e = 0; e < 8; ++e) {
      const uint4* src = (const uint4*)(kb + ((size_t)(b * 8 + e) * 224 + j) * 16);
      *(uint4*)&Ksh[j * 136 + e * 16] = src[0];
      *(uint4*)&Ksh[j * 136 + e * 16 + 8] = src[1];
    }
    float gs = 0.f, ds = 0.f;
#pragma unroll
    for (int e = 0; e < 8; ++e) {
      gs += GAMMA[((size_t)(b * 8 + e)) * 224 + j];
      ds += DELTA[((size_t)(b * 8 + e)) * 224 + j];
    }
    Gs[j] = gs;
    Ds[j] = ds;
  }
  __syncthreads();
  const int wid = tid >> 6, lane = tid & 63;
  const int g = lane >> 4, li = lane & 15;
  const int i = blockIdx.y * 112 + wid * 16 + li;
  bf16x8 Bq[4];
#pragma unroll
  for (int ks = 0; ks < 4; ++ks) {
    const int e2 = ks * 2 + (g >> 1), c0 = (g & 1) * 8;
    Bq[ks] = *(const bf16x8*)&qb[((size_t)(b * 8 + e2) * 224 + i) * 16 + c0];
  }
  f32x4 C[14];
#pragma unroll
  for (int js = 0; js < 14; ++js) {
    f32x4 acc = {0.f, 0.f, 0.f, 0.f};
#pragma unroll
    for (int ks = 0; ks < 4; ++ks) {
      const bf16x8 A = *(const bf16x8*)&Ksh[(js * 16 + li) * 136 + ks * 32 + g * 8];
      acc = __builtin_amdgcn_mfma_f32_16x16x32_bf16(A, Bq[ks], acc, 0, 0, 0);
    }
    C[js] = acc;
  }
  float ai = 0.f, bi_ = 0.f;
#pragma unroll
  for (int e = 0; e < 8; ++e) {
    ai += ALPHA[((size_t)(b * 8 + e)) * 224 + i];
    bi_ += BETA[((size_t)(b * 8 + e)) * 224 + i];
  }
  const float ifl = (float)i;
  float m = -1e30f;
#pragma unroll
  for (int js = 0; js < 14; ++js) {
#pragma unroll
    for (int r = 0; r < 4; ++r) {
      const int j = js * 16 + g * 4 + r;
      float s = C[js][r] + ((float)j - ifl) * (ai + Gs[j]) + bi_ + Ds[j];
      C[js][r] = s;
      m = fmaxf(m, s);
    }
  }
  m = fmaxf(m, __shfl_xor(m, 16));
  m = fmaxf(m, __shfl_xor(m, 32));
  float l = 0.f, wj = 0.f;
#pragma unroll
  for (int js = 0; js < 14; ++js) {
#pragma unroll
    for (int r = 0; r < 4; ++r) {
      const float p = __expf(C[js][r] - m);
      l += p;
      wj += p * (float)(js * 16 + g * 4 + r);
    }
  }
  l += __shfl_xor(l, 16);
  l += __shfl_xor(l, 32);
  wj += __shfl_xor(wj, 16);
  wj += __shfl_xor(wj, 32);
  if (g == 0) out[(size_t)b * 224 + i] = ifl - wj / fmaxf(l, 1e-30f);
}

// Single-launch conversion of all five weight tensors to one bf16 buffer.
#define OFF_FEAT 0
#define OFF_SWI 16384
#define OFF_SWO 311296
#define OFF_CWI 409600
#define OFF_CWO 704512
#define N_WALL 802816
__global__ __launch_bounds__(256) void cvt_all_kernel(
    const float* __restrict__ feat_w, const float* __restrict__ self_Wi,
    const float* __restrict__ self_Wo, const float* __restrict__ cross_Wi,
    const float* __restrict__ cross_Wo, u16* __restrict__ dst) {
  int idx = blockIdx.x * 256 + threadIdx.x;
  if (idx >= N_WALL) return;
  float v;
  if (idx < OFF_SWI)       v = feat_w[idx];
  else if (idx < OFF_SWO)  v = self_Wi[idx - OFF_SWI];
  else if (idx < OFF_CWI)  v = self_Wo[idx - OFF_SWO];
  else if (idx < OFF_CWO)  v = cross_Wi[idx - OFF_CWI];
  else                     v = cross_Wo[idx - OFF_CWO];
  dst[idx] = f2bf(v);
}

extern "C" void kernel_launch(void* const* d_in, const int* in_sizes, int n_in,
                              void* d_out, int out_size, void* d_ws, size_t ws_size,
                              hipStream_t stream) {
  (void)in_sizes; (void)n_in; (void)out_size; (void)ws_size;
  const float* x_l = (const float*)d_in[0];
  const float* x_r = (const float*)d_in[1];
  const float* feat_w = (const float*)d_in[2];
  const float* feat_b = (const float*)d_in[3];
  const float* self_Wi = (const float*)d_in[4];
  const float* self_bi = (const float*)d_in[5];
  const float* self_Wo = (const float*)d_in[6];
  const float* self_bo = (const float*)d_in[7];
  const float* cross_Wi = (const float*)d_in[8];
  const float* cross_bi = (const float*)d_in[9];
  const float* cross_Wo = (const float*)d_in[10];
  const float* cross_bo = (const float*)d_in[11];
  const float* ln_g = (const float*)d_in[12];
  const float* ln_b = (const float*)d_in[13];

  char* ws = (char*)d_ws;
  size_t off = 0;
  auto alloc = [&](size_t bytes) {
    char* p = ws + off;
    off += (bytes + 255) & ~(size_t)255;
    return p;
  };
  // Total ~97 MB — under the R6-proven ~112 MB budget. XB aliases OB:
  // XB live range is tab->qkv, OB live range is attn->out-proj (disjoint).
  float* XA = (float*)alloc((size_t)2 * ROWS_ * C_ * 4);   // residual (in-place LN)
  u16* QB = (u16*)alloc((size_t)256 * NH * W_ * HD * 2);   // also XT scratch
  u16* KB = (u16*)alloc((size_t)256 * NH * W_ * HD * 2);
  u16* VB = (u16*)alloc((size_t)256 * NH * W_ * HD * 2);
  u16* OB = (u16*)alloc((size_t)2 * ROWS_ * C_ * 2);
  u16* WALL = (u16*)alloc((size_t)N_WALL * 2);
  float* PREP = (float*)alloc((size_t)12 * PREP_STRIDE * 4);
  float* ALPHA = (float*)alloc((size_t)256 * NH * W_ * 4);
  float* BETA = (float*)alloc((size_t)256 * NH * W_ * 4);
  float* GAMMA = (float*)alloc((size_t)256 * NH * W_ * 4);
  float* DELTA = (float*)alloc((size_t)256 * NH * W_ * 4);
  u16* XB = OB;   // alias — disjoint live ranges

  cvt_all_kernel<<<3136, 256, 0, stream>>>(feat_w, self_Wi, self_Wo, cross_Wi, cross_Wo, WALL);
  prep_kernel<<<dim3(12, 8), 256, 0, stream>>>(self_Wi, self_bi, cross_Wi, cross_bi, PREP);

  transpose_kernel<<<dim3(4, 64, 4), 256, 0, stream>>>(x_l, x_r, QB);
  gemm_plain<<<dim3(896, 2), 256, 0, stream>>>(QB, WALL + OFF_FEAT, feat_b, 5, XA);

  for (int l = 0; l < 6; ++l) {
    const u16* sWi = WALL + OFF_SWI + (size_t)l * 384 * 128;
    const u16* sWo = WALL + OFF_SWO + (size_t)l * 128 * 128;
    const u16* cWi = WALL + OFF_CWI + (size_t)l * 384 * 128;
    const u16* cWo = WALL + OFF_CWO + (size_t)l * 128 * 128;
    const float* sbi = self_bi + l * 384;
    const float* sbo = self_bo + l * 128;
    const float* cbi = cross_bi + l * 384;
    const float* cbo = cross_bo + l * 128;
    const float* ps = PREP + (size_t)(l * 2) * PREP_STRIDE;
    const float* pc = PREP + (size_t)(l * 2 + 1) * PREP_STRIDE;

    // --- self attention on xl AND xr: X = LN(X) (+tables+XB), qkv, attn, +=proj ---
    tab_kernel<<<1792, 256, 0, stream>>>(XA, ln_g, ln_b, ps, ps + 4096, ALPHA, BETA,
                                         ps + 2048, ps + 4112, GAMMA, DELTA, XB, 0);
    gemm_qkv_self<<<dim3(448, 3), 512, 0, stream>>>(XB, sWi, sbi, QB, KB, VB);
    attn_kernel<<<dim3(8, 256), 448, 0, stream>>>(QB, KB, VB, ALPHA, BETA, GAMMA, DELTA, OB);
    gemm_plain<<<dim3(896, 2), 256, 0, stream>>>(OB, sWo, sbo, 4, XA);

    // --- cross attention: q from xr, k/v from xl; X = LN(X) first ---
    tab_kernel<<<1792, 256, 0, stream>>>(XA, ln_g, ln_b, pc, pc + 4096, ALPHA, BETA,
                                         pc + 2048, pc + 4112, GAMMA, DELTA, XB, 1);
    // l==5: V (y=2) is dead — no attn launch follows and corresp reads QB/KB only.
    gemm_qkv_cross<<<dim3(224, (l < 5) ? 3 : 2), 512, 0, stream>>>(
        XB, XB + (size_t)ROWS_ * C_, cWi, cbi, QB, KB, VB);
    if (l < 5) {
      attn_kernel<<<dim3(8, 128), 448, 0, stream>>>(QB, KB, VB, ALPHA, BETA, GAMMA, DELTA, OB);
      gemm_plain<<<dim3(448, 2), 256, 0, stream>>>(OB, cWo, cbo, 4, XA);  // xl half only
    }
    // l == 5: attention output / x updates dead; corresp reads QB/KB + tables.
  }
  corresp_kernel<<<dim3(128, 2), 448, 0, stream>>>(QB, KB, ALPHA, BETA, GAMMA, DELTA,
                                                   (float*)d_out);
}